// Round 6
// baseline (2084.478 us; speedup 1.0000x reference)
//
#include <hip/hip_runtime.h>
#include <hip/hip_bf16.h>
#include <math.h>
#include <stdint.h>

#define L 2048
#define D 768
#define H 12
#define DH 64
#define F 3072
#define NL 12
#define QKVN 2304

typedef __attribute__((ext_vector_type(8))) short bf16x8;
typedef __attribute__((ext_vector_type(4))) float f32x4;

__device__ __forceinline__ ushort f2bf(float x) {
    union { float f; uint32_t u; } c; c.f = x;
    uint32_t r = c.u + 0x7FFFu + ((c.u >> 16) & 1u);
    return (ushort)(r >> 16);
}

// pack two f32 -> one dword of two bf16 (RNE)
__device__ __forceinline__ uint32_t cvt_pk_bf16(float lo, float hi) {
    uint32_t r;
    asm("v_cvt_pk_bf16_f32 %0, %1, %2" : "=v"(r) : "v"(lo), "v"(hi));
    return r;
}

__device__ __forceinline__ bf16x8 ldfrag(const ushort* p) {
    ushort4 lo = *(const ushort4*)(p);
    ushort4 hi = *(const ushort4*)(p + 16);
    bf16x8 f;
    f[0] = (short)lo.x; f[1] = (short)lo.y; f[2] = (short)lo.z; f[3] = (short)lo.w;
    f[4] = (short)hi.x; f[5] = (short)hi.y; f[6] = (short)hi.z; f[7] = (short)hi.w;
    return f;
}

__device__ __forceinline__ float gelu_tanh(float x) {
    float c = 0.7978845608028654f;
    float inner = c * (x + 0.044715f * x * x * x);
    return 0.5f * x * (1.0f + tanhf(inner));
}

// ---------------- position cumsum ----------------
__global__ void pos_kernel(const int* __restrict__ mask, int* __restrict__ pos) {
    __shared__ int sm[L];
    for (int i = threadIdx.x; i < L; i += blockDim.x) sm[i] = mask[i];
    __syncthreads();
    int t = blockIdx.x * blockDim.x + threadIdx.x;
    if (t < L) {
        int s = 0;
        for (int j = 0; j <= t; ++j) s += sm[j];
        int p = s - 1;
        if (sm[t] == 0) p = 1;
        pos[t] = p;
    }
}

__global__ void maskb_kernel(const int* __restrict__ mask, float* __restrict__ mb) {
    int i = blockIdx.x * blockDim.x + threadIdx.x;
    if (i < L) mb[i] = mask[i] ? 0.f : -1e9f;
}

// ---------------- embedding ----------------
__global__ __launch_bounds__(256) void embed_kernel(const int* __restrict__ ids,
                                                    const int* __restrict__ pos,
                                                    const float* __restrict__ wte,
                                                    const float* __restrict__ wpe,
                                                    float* __restrict__ h) {
    int t = blockIdx.x;
    int id = ids[t];
    int p = pos[t];
    const float* we = wte + (size_t)id * D;
    const float* wp = wpe + (size_t)p * D;
    float* hr = h + (size_t)t * D;
#pragma unroll
    for (int i = 0; i < 3; ++i) {
        int d = threadIdx.x + i * 256;
        hr[d] = we[d] + wp[d];
    }
}

// ---------------- layernorm (f32 in, bf16 or f32 out) ----------------
template <bool OUTBF>
__global__ __launch_bounds__(256) void ln_kernel(const float* __restrict__ in,
                                                 const float* __restrict__ w,
                                                 const float* __restrict__ b,
                                                 float* __restrict__ outF,
                                                 ushort* __restrict__ outB) {
    __shared__ float red[2][4];
    int row = blockIdx.x;
    const float* x = in + (size_t)row * D;
    int t = threadIdx.x;
    float v0 = x[t], v1 = x[t + 256], v2 = x[t + 512];
    float s = v0 + v1 + v2;
    float ss = v0 * v0 + v1 * v1 + v2 * v2;
#pragma unroll
    for (int o = 32; o; o >>= 1) {
        s += __shfl_xor(s, o);
        ss += __shfl_xor(ss, o);
    }
    int wave = t >> 6;
    if ((t & 63) == 0) { red[0][wave] = s; red[1][wave] = ss; }
    __syncthreads();
    s = red[0][0] + red[0][1] + red[0][2] + red[0][3];
    ss = red[1][0] + red[1][1] + red[1][2] + red[1][3];
    float mean = s * (1.f / D);
    float var = ss * (1.f / D) - mean * mean;
    float rstd = rsqrtf(var + 1e-5f);
#pragma unroll
    for (int i = 0; i < 3; ++i) {
        int d = t + i * 256;
        float vv = (i == 0) ? v0 : (i == 1) ? v1 : v2;
        float y = (vv - mean) * rstd * w[d] + b[d];
        if (OUTBF) outB[(size_t)row * D + d] = f2bf(y);
        else       outF[(size_t)row * D + d] = y;
    }
}

// ---------------- transpose-cast f32 [K][N] -> bf16 [N][K], z = layer ----------------
__global__ __launch_bounds__(256) void tcast_f32(const float* __restrict__ in,
                                                 ushort* __restrict__ out,
                                                 int K, int N,
                                                 size_t inStride, size_t outStride) {
    in += blockIdx.z * inStride;
    out += blockIdx.z * outStride;
    __shared__ float tile[64][65];
    int k0 = blockIdx.y * 64, n0 = blockIdx.x * 64;
    int t = threadIdx.x;
    int cl = t & 63, rg = t >> 6;
#pragma unroll
    for (int i = 0; i < 16; ++i) {
        int r = rg + 4 * i;
        tile[r][cl] = in[(size_t)(k0 + r) * N + n0 + cl];
    }
    __syncthreads();
#pragma unroll
    for (int i = 0; i < 16; ++i) {
        int r = rg + 4 * i;
        out[(size_t)(n0 + r) * K + k0 + cl] = f2bf(tile[cl][r]);
    }
}

// ---------------- bf16 MFMA GEMM, 128x128 tile, BK=32, dbuf, 1 barrier/step ----
// VSPLIT: for the QKV GEMM, cols >= 2*D (the V projection) are written
// transposed into vTout[(col-2D)*L + row] instead of outB.
template <int ACT, bool OUTBF, bool VSPLIT>
__global__ __launch_bounds__(256) void gemm_bf16(const ushort* __restrict__ A,
                                                 const ushort* __restrict__ Bt,
                                                 const float* __restrict__ bias,
                                                 const float* __restrict__ resid,
                                                 float* __restrict__ outF,
                                                 ushort* __restrict__ outB,
                                                 ushort* __restrict__ vTout,
                                                 int M, int N, int K) {
    __shared__ __align__(16) char lds[32768];   // 2 x (A 8K + B 8K)
    const int tid = threadIdx.x;
    const int lane = tid & 63, w = tid >> 6;
    const int wr = w >> 1, wc = w & 1;
    const int bm = blockIdx.y * 128, bn = blockIdx.x * 128;
    const int l15 = lane & 15, l4 = lane >> 4;
    const int srow = tid >> 2, c = tid & 3;
    const int blo = (c & 1) * 32 + (c >> 1) * 8;

    const int sxor = (srow & 3) << 4;
    const int wo0 = srow * 64 + (blo ^ sxor);
    const int wo1 = srow * 64 + ((blo + 16) ^ sxor);
    const int rxor = (l4 * 16) ^ ((l15 & 3) << 4);
    const int aBase = (wr * 64 + l15) * 64 + rxor;
    const int bBase = (wc * 64 + l15) * 64 + rxor;

    f32x4 acc[4][4];
#pragma unroll
    for (int m = 0; m < 4; ++m)
#pragma unroll
        for (int n = 0; n < 4; ++n)
            acc[m][n] = (f32x4){0.f, 0.f, 0.f, 0.f};

    const ushort* Ag = A + (size_t)(bm + srow) * K + c * 8;
    const ushort* Ag2 = Ag + (size_t)64 * K;
    const ushort* Bg = Bt + (size_t)(bn + srow) * K + c * 8;
    const ushort* Bg2 = Bg + (size_t)64 * K;

    uint4 a0 = *(const uint4*)(Ag);
    uint4 a1 = *(const uint4*)(Ag2);
    uint4 b0 = *(const uint4*)(Bg);
    uint4 b1 = *(const uint4*)(Bg2);

    for (int k0 = 0; k0 < K; k0 += 32) {
        char* Ab = lds + ((k0 >> 5) & 1) * 16384;
        char* Bb = Ab + 8192;
        uint2 t0, t1;
        t0.x = a0.x; t0.y = a0.y; t1.x = a0.z; t1.y = a0.w;
        *(uint2*)(Ab + wo0) = t0;
        *(uint2*)(Ab + wo1) = t1;
        t0.x = a1.x; t0.y = a1.y; t1.x = a1.z; t1.y = a1.w;
        *(uint2*)(Ab + wo0 + 4096) = t0;
        *(uint2*)(Ab + wo1 + 4096) = t1;
        t0.x = b0.x; t0.y = b0.y; t1.x = b0.z; t1.y = b0.w;
        *(uint2*)(Bb + wo0) = t0;
        *(uint2*)(Bb + wo1) = t1;
        t0.x = b1.x; t0.y = b1.y; t1.x = b1.z; t1.y = b1.w;
        *(uint2*)(Bb + wo0 + 4096) = t0;
        *(uint2*)(Bb + wo1 + 4096) = t1;
        __syncthreads();
        if (k0 + 32 < K) {
            a0 = *(const uint4*)(Ag + k0 + 32);
            a1 = *(const uint4*)(Ag2 + k0 + 32);
            b0 = *(const uint4*)(Bg + k0 + 32);
            b1 = *(const uint4*)(Bg2 + k0 + 32);
        }
        bf16x8 af[4], bfv[4];
#pragma unroll
        for (int m = 0; m < 4; ++m)
            af[m] = *(const bf16x8*)(Ab + aBase + m * 1024);
#pragma unroll
        for (int n = 0; n < 4; ++n)
            bfv[n] = *(const bf16x8*)(Bb + bBase + n * 1024);
#pragma unroll
        for (int m = 0; m < 4; ++m)
#pragma unroll
            for (int n = 0; n < 4; ++n)
                acc[m][n] = __builtin_amdgcn_mfma_f32_16x16x32_bf16(af[m], bfv[n], acc[m][n], 0, 0, 0);
    }

#pragma unroll
    for (int m = 0; m < 4; ++m)
#pragma unroll
        for (int n = 0; n < 4; ++n) {
            int col = bn + wc * 64 + n * 16 + l15;
            int row0 = bm + wr * 64 + m * 16 + l4 * 4;
            if (VSPLIT && col >= 2 * D) {
                ushort4 pk;
                pk.x = f2bf(acc[m][n][0]);
                pk.y = f2bf(acc[m][n][1]);
                pk.z = f2bf(acc[m][n][2]);
                pk.w = f2bf(acc[m][n][3]);
                *(ushort4*)(vTout + (size_t)(col - 2 * D) * L + row0) = pk;
            } else {
#pragma unroll
                for (int r = 0; r < 4; ++r) {
                    int row = row0 + r;
                    float v = acc[m][n][r];
                    if (bias) v += bias[col];
                    if (ACT == 1) v = gelu_tanh(v);
                    if (resid) v += resid[(size_t)row * N + col];
                    if (OUTBF) outB[(size_t)row * N + col] = f2bf(v);
                    else       outF[(size_t)row * N + col] = v;
                }
            }
        }
}

// ---------------- bf16 MFMA GEMM, 64x64 tile, BK=64, dbuf, no split-K ----------
// For N=768 GEMMs (o-proj, pw): grid (N/64, M/64) = 384 blocks. Epilogue fuses
// bias + residual and writes f32 h in place. LDS rows = 128B (64 k-elems),
// k-permuted 16B chunks + (row&7)<<4 XOR so a fragment = one clean b128.
__global__ __launch_bounds__(256) void gemm64_bf16(const ushort* __restrict__ A,
                                                   const ushort* __restrict__ Bt,
                                                   const float* __restrict__ bias,
                                                   float* __restrict__ h,
                                                   int M, int N, int K) {
    __shared__ __align__(16) char lds[32768];   // 2 x (A 8K + B 8K)
    const int tid = threadIdx.x;
    const int lane = tid & 63, w = tid >> 6;
    const int wr = w >> 1, wc = w & 1;
    const int bm = blockIdx.y * 64, bn = blockIdx.x * 64;
    const int l15 = lane & 15, l4 = lane >> 4;
    const int srow = tid >> 2, q = tid & 3;
    const int swz = (srow & 7) << 4;
    const int rb = srow * 128;
    int offlo[2], offhi[2];
#pragma unroll
    for (int i = 0; i < 2; ++i) {
        int g = 2 * q + i;
        int cc = g & 3, hf = g >> 2;
        int blo = (cc & 1) * 32 + ((cc >> 1) & 1) * 8 + hf * 64;
        offlo[i] = rb + ((blo & 0x70) ^ swz) + (blo & 15);
        int bhi = blo + 16;
        offhi[i] = rb + ((bhi & 0x70) ^ swz) + (bhi & 15);
    }
    const int fxor = (l15 & 7) << 4;

    f32x4 acc[2][2];
#pragma unroll
    for (int m = 0; m < 2; ++m)
#pragma unroll
        for (int n = 0; n < 2; ++n)
            acc[m][n] = (f32x4){0.f, 0.f, 0.f, 0.f};

    const ushort* Ag = A + (size_t)(bm + srow) * K + q * 16;
    const ushort* Bg = Bt + (size_t)(bn + srow) * K + q * 16;

    uint4 a0 = *(const uint4*)(Ag);
    uint4 a1 = *(const uint4*)(Ag + 8);
    uint4 b0 = *(const uint4*)(Bg);
    uint4 b1 = *(const uint4*)(Bg + 8);

    for (int k0 = 0; k0 < K; k0 += 64) {
        char* Ab = lds + ((k0 >> 6) & 1) * 16384;
        char* Bb = Ab + 8192;
        uint2 t0, t1;
        t0.x = a0.x; t0.y = a0.y; t1.x = a0.z; t1.y = a0.w;
        *(uint2*)(Ab + offlo[0]) = t0;
        *(uint2*)(Ab + offhi[0]) = t1;
        t0.x = a1.x; t0.y = a1.y; t1.x = a1.z; t1.y = a1.w;
        *(uint2*)(Ab + offlo[1]) = t0;
        *(uint2*)(Ab + offhi[1]) = t1;
        t0.x = b0.x; t0.y = b0.y; t1.x = b0.z; t1.y = b0.w;
        *(uint2*)(Bb + offlo[0]) = t0;
        *(uint2*)(Bb + offhi[0]) = t1;
        t0.x = b1.x; t0.y = b1.y; t1.x = b1.z; t1.y = b1.w;
        *(uint2*)(Bb + offlo[1]) = t0;
        *(uint2*)(Bb + offhi[1]) = t1;
        __syncthreads();
        if (k0 + 64 < K) {
            a0 = *(const uint4*)(Ag + k0 + 64);
            a1 = *(const uint4*)(Ag + k0 + 72);
            b0 = *(const uint4*)(Bg + k0 + 64);
            b1 = *(const uint4*)(Bg + k0 + 72);
        }
        bf16x8 af[2][2], bfv[2][2];
#pragma unroll
        for (int m = 0; m < 2; ++m)
#pragma unroll
            for (int ks = 0; ks < 2; ++ks)
                af[m][ks] = *(const bf16x8*)(Ab + (wr * 32 + m * 16 + l15) * 128 +
                                             ((ks * 64 + l4 * 16) ^ fxor));
#pragma unroll
        for (int n = 0; n < 2; ++n)
#pragma unroll
            for (int ks = 0; ks < 2; ++ks)
                bfv[n][ks] = *(const bf16x8*)(Bb + (wc * 32 + n * 16 + l15) * 128 +
                                              ((ks * 64 + l4 * 16) ^ fxor));
#pragma unroll
        for (int m = 0; m < 2; ++m)
#pragma unroll
            for (int n = 0; n < 2; ++n)
#pragma unroll
                for (int ks = 0; ks < 2; ++ks)
                    acc[m][n] = __builtin_amdgcn_mfma_f32_16x16x32_bf16(
                        af[m][ks], bfv[n][ks], acc[m][n], 0, 0, 0);
    }

#pragma unroll
    for (int m = 0; m < 2; ++m)
#pragma unroll
        for (int n = 0; n < 2; ++n) {
            int col = bn + wc * 32 + n * 16 + l15;
#pragma unroll
            for (int r = 0; r < 4; ++r) {
                int row = bm + wr * 32 + m * 16 + l4 * 4 + r;
                float v = acc[m][n][r] + bias[col] + h[(size_t)row * N + col];
                h[(size_t)row * N + col] = v;
            }
        }
}

// ---------------- MFMA flash attention, QBLK=32, 2 waves, KVBLK=64, dbuf ----
__global__ __launch_bounds__(128) void attn_kernel(const ushort* __restrict__ qkv,
                                                   const ushort* __restrict__ vT,
                                                   const float* __restrict__ maskb,
                                                   ushort* __restrict__ ctx) {
    __shared__ __align__(16) char Kl[2][8192];
    __shared__ __align__(16) char Vl[2][8192];
    __shared__ float Ml[2][64];
    const int hh = blockIdx.y;
    const int q0 = ((int)gridDim.x - 1 - (int)blockIdx.x) * 32;  // long blocks first
    const int tid = threadIdx.x;
    const int lane = tid & 63, w = tid >> 6;
    const int l15 = lane & 15, l4 = lane >> 4;
    const int qg = q0 + w * 16 + l15;
    const int qmin = q0 + w * 16;   // wave-uniform

    bf16x8 qf[2];
#pragma unroll
    for (int ks = 0; ks < 2; ++ks)
        qf[ks] = ldfrag(qkv + (size_t)qg * QKVN + hh * 64 + ks * 32 + l4 * 4);

    f32x4 o[4];
#pragma unroll
    for (int i = 0; i < 4; ++i) o[i] = (f32x4){0.f, 0.f, 0.f, 0.f};
    float mrun = -1e30f, lrun = 0.f;

    // staging: 128 threads, thread = (row srow, 64B-half hf); 4 x 16B chunks
    const int srow = tid >> 1, hf = tid & 1;
    const int swz = (srow & 7) << 4;
    const int rb = srow * 128;
    int offlo[4], offhi[4];
#pragma unroll
    for (int cc = 0; cc < 4; ++cc) {
        int blo = (cc & 1) * 32 + ((cc >> 1) & 1) * 8 + hf * 64;
        offlo[cc] = rb + ((blo & 0x70) ^ swz) + (blo & 15);
        int bhi = blo + 16;
        offhi[cc] = rb + ((bhi & 0x70) ^ swz) + (bhi & 15);
    }
    const int fxor = (l15 & 7) << 4;

    const ushort* Ksrc = qkv + (size_t)srow * QKVN + D + hh * 64 + hf * 32;
    const ushort* Vsrc = vT + (size_t)(hh * 64 + srow) * L + hf * 32;

    uint4 kx[4], vx[4];
    float mv = 0.f;
    const int nt = q0 / 64 + 1;

#pragma unroll
    for (int cc = 0; cc < 4; ++cc) {
        kx[cc] = *(const uint4*)(Ksrc + cc * 8);
        vx[cc] = *(const uint4*)(Vsrc + cc * 8);
    }
    if (tid < 64) mv = maskb[tid];

    for (int it = 0; it < nt; ++it) {
        const int kv0 = it * 64;
        const int b = it & 1;
        {
            char* Kb = Kl[b];
            char* Vb = Vl[b];
            uint2 t0, t1;
#pragma unroll
            for (int cc = 0; cc < 4; ++cc) {
                t0.x = kx[cc].x; t0.y = kx[cc].y; t1.x = kx[cc].z; t1.y = kx[cc].w;
                *(uint2*)(Kb + offlo[cc]) = t0;
                *(uint2*)(Kb + offhi[cc]) = t1;
                t0.x = vx[cc].x; t0.y = vx[cc].y; t1.x = vx[cc].z; t1.y = vx[cc].w;
                *(uint2*)(Vb + offlo[cc]) = t0;
                *(uint2*)(Vb + offhi[cc]) = t1;
            }
            if (tid < 64) Ml[b][tid] = mv;
        }
        __syncthreads();
        if (it + 1 < nt) {
            const size_t koff = (size_t)(kv0 + 64) * QKVN;
#pragma unroll
            for (int cc = 0; cc < 4; ++cc) {
                kx[cc] = *(const uint4*)(Ksrc + koff + cc * 8);
                vx[cc] = *(const uint4*)(Vsrc + kv0 + 64 + cc * 8);
            }
            if (tid < 64) mv = maskb[kv0 + 64 + tid];
        }

        const char* Kb = Kl[b];
        const char* Vb = Vl[b];

        f32x4 st[4];
#pragma unroll
        for (int m = 0; m < 4; ++m) st[m] = (f32x4){0.f, 0.f, 0.f, 0.f};
#pragma unroll
        for (int m = 0; m < 4; ++m)
#pragma unroll
            for (int ks = 0; ks < 2; ++ks) {
                bf16x8 kf = *(const bf16x8*)(Kb + (m * 16 + l15) * 128 +
                                             ((ks * 64 + l4 * 16) ^ fxor));
                st[m] = __builtin_amdgcn_mfma_f32_16x16x32_bf16(kf, qf[ks], st[m], 0, 0, 0);
            }

        float p[4][4];
        float tmax = -1e30f;
        const bool full = (kv0 + 63 <= qmin);
        if (full) {
#pragma unroll
            for (int m = 0; m < 4; ++m)
#pragma unroll
                for (int r = 0; r < 4; ++r) {
                    int kl = m * 16 + l4 * 4 + r;
                    float s = st[m][r] + Ml[b][kl];
                    p[m][r] = s;
                    tmax = fmaxf(tmax, s);
                }
        } else {
#pragma unroll
            for (int m = 0; m < 4; ++m)
#pragma unroll
                for (int r = 0; r < 4; ++r) {
                    int kl = m * 16 + l4 * 4 + r;
                    float s = st[m][r] + Ml[b][kl];
                    if (kv0 + kl > qg) s = -1e30f;
                    p[m][r] = s;
                    tmax = fmaxf(tmax, s);
                }
        }
        tmax = fmaxf(tmax, __shfl_xor(tmax, 16));
        tmax = fmaxf(tmax, __shfl_xor(tmax, 32));
        const bool noresc = __all(tmax <= mrun);
        float mnew = noresc ? mrun : fmaxf(mrun, tmax);
        float scale = noresc ? 1.f : __expf(mrun - mnew);
        float ts = 0.f;
#pragma unroll
        for (int m = 0; m < 4; ++m)
#pragma unroll
            for (int r = 0; r < 4; ++r) {
                float e = __expf(p[m][r] - mnew);
                p[m][r] = e;
                ts += e;
            }
        ts += __shfl_xor(ts, 16);
        ts += __shfl_xor(ts, 32);
        lrun = lrun * scale + ts;
        mrun = mnew;

        bf16x8 pf[2];
#pragma unroll
        for (int g = 0; g < 2; ++g) {
            union { bf16x8 v; uint32_t d[4]; } pu;
            pu.d[0] = cvt_pk_bf16(p[2 * g][0], p[2 * g][1]);
            pu.d[1] = cvt_pk_bf16(p[2 * g][2], p[2 * g][3]);
            pu.d[2] = cvt_pk_bf16(p[2 * g + 1][0], p[2 * g + 1][1]);
            pu.d[3] = cvt_pk_bf16(p[2 * g + 1][2], p[2 * g + 1][3]);
            pf[g] = pu.v;
        }
        if (!noresc) {
#pragma unroll
            for (int i = 0; i < 4; ++i) {
                o[i][0] *= scale; o[i][1] *= scale; o[i][2] *= scale; o[i][3] *= scale;
            }
        }
#pragma unroll
        for (int dhb = 0; dhb < 4; ++dhb)
#pragma unroll
            for (int g = 0; g < 2; ++g) {
                bf16x8 vf = *(const bf16x8*)(Vb + (dhb * 16 + l15) * 128 +
                                             ((g * 64 + l4 * 16) ^ fxor));
                o[dhb] = __builtin_amdgcn_mfma_f32_16x16x32_bf16(vf, pf[g], o[dhb], 0, 0, 0);
            }
    }

    float rinv = 1.0f / lrun;
#pragma unroll
    for (int dhb = 0; dhb < 4; ++dhb) {
        ushort4 pk;
        pk.x = f2bf(o[dhb][0] * rinv);
        pk.y = f2bf(o[dhb][1] * rinv);
        pk.z = f2bf(o[dhb][2] * rinv);
        pk.w = f2bf(o[dhb][3] * rinv);
        *(ushort4*)(ctx + (size_t)qg * D + hh * 64 + dhb * 16 + l4 * 4) = pk;
    }
}

extern "C" void kernel_launch(void* const* d_in, const int* in_sizes, int n_in,
                              void* d_out, int out_size, void* d_ws, size_t ws_size,
                              hipStream_t stream) {
    const int* ids = (const int*)d_in[0];
    const int* amask = (const int*)d_in[1];
    const float* wte = (const float*)d_in[2];
    const float* wpe = (const float*)d_in[3];
    const float* lnf_w = (const float*)d_in[4];
    const float* lnf_b = (const float*)d_in[5];
    const float* ln1_w = (const float*)d_in[6];
    const float* ln1_b = (const float*)d_in[7];
    const float* qw = (const float*)d_in[8];
    const float* kw = (const float*)d_in[9];
    const float* vw = (const float*)d_in[10];
    const float* ow = (const float*)d_in[11];
    const float* ob = (const float*)d_in[12];
    const float* ln2_w = (const float*)d_in[13];
    const float* ln2_b = (const float*)d_in[14];
    const float* fcw = (const float*)d_in[15];
    const float* fcb = (const float*)d_in[16];
    const float* pw = (const float*)d_in[17];
    const float* pb = (const float*)d_in[18];

    char* p = (char*)d_ws;
    auto take = [&](size_t bytes) -> char* {
        char* r = p;
        p += (bytes + 4095) & ~(size_t)4095;
        return r;
    };
    ushort* wqkvT = (ushort*)take((size_t)NL * QKVN * D * 2);
    ushort* woT   = (ushort*)take((size_t)NL * D * D * 2);
    ushort* fcwT  = (ushort*)take((size_t)NL * F * D * 2);
    ushort* pwT   = (ushort*)take((size_t)NL * D * F * 2);
    float*  h     = (float*)take((size_t)L * D * 4);
    ushort* xb    = (ushort*)take((size_t)L * D * 2);
    ushort* qkvb  = (ushort*)take((size_t)L * QKVN * 2);
    ushort* vTb   = (ushort*)take((size_t)D * L * 2);
    ushort* ctxb  = (ushort*)take((size_t)L * D * 2);
    ushort* f1b   = (ushort*)take((size_t)L * F * 2);
    float*  mb    = (float*)take(L * 4);
    int*    pos   = (int*)take(L * 4);

    pos_kernel<<<8, 256, 0, stream>>>(amask, pos);
    maskb_kernel<<<8, 256, 0, stream>>>(amask, mb);
    embed_kernel<<<L, 256, 0, stream>>>(ids, pos, wte, wpe, h);

    tcast_f32<<<dim3(12, 12, NL), 256, 0, stream>>>(qw, wqkvT, D, D,
                                                    (size_t)D * D, (size_t)QKVN * D);
    tcast_f32<<<dim3(12, 12, NL), 256, 0, stream>>>(kw, wqkvT + (size_t)D * D, D, D,
                                                    (size_t)D * D, (size_t)QKVN * D);
    tcast_f32<<<dim3(12, 12, NL), 256, 0, stream>>>(vw, wqkvT + (size_t)2 * D * D, D, D,
                                                    (size_t)D * D, (size_t)QKVN * D);
    tcast_f32<<<dim3(12, 12, NL), 256, 0, stream>>>(ow, woT, D, D,
                                                    (size_t)D * D, (size_t)D * D);
    tcast_f32<<<dim3(48, 12, NL), 256, 0, stream>>>(fcw, fcwT, D, F,
                                                    (size_t)D * F, (size_t)F * D);
    tcast_f32<<<dim3(12, 48, NL), 256, 0, stream>>>(pw, pwT, F, D,
                                                    (size_t)F * D, (size_t)D * F);

    ln_kernel<true><<<L, 256, 0, stream>>>(h, ln1_w, ln1_b, nullptr, xb);

    for (int l = 0; l < NL; ++l) {
        gemm_bf16<0, true, true><<<dim3(QKVN / 128, L / 128), 256, 0, stream>>>(
            xb, wqkvT + (size_t)l * QKVN * D, nullptr, nullptr, nullptr, qkvb,
            vTb, L, QKVN, D);
        attn_kernel<<<dim3(L / 32, H), 128, 0, stream>>>(qkvb, vTb, mb, ctxb);
        gemm64_bf16<<<dim3(D / 64, L / 64), 256, 0, stream>>>(
            ctxb, woT + (size_t)l * D * D, ob + l * D, h, L, D, D);
        ln_kernel<true><<<L, 256, 0, stream>>>(h, ln2_w + l * D, ln2_b + l * D,
                                               nullptr, xb);
        gemm_bf16<1, true, false><<<dim3(F / 128, L / 128), 256, 0, stream>>>(
            xb, fcwT + (size_t)l * F * D, fcb + l * F, nullptr, nullptr, f1b,
            nullptr, L, F, D);
        gemm64_bf16<<<dim3(D / 64, L / 64), 256, 0, stream>>>(
            f1b, pwT + (size_t)l * D * F, pb + l * D, h, L, D, F);
        if (l < NL - 1) {
            ln_kernel<true><<<L, 256, 0, stream>>>(h, ln1_w + (l + 1) * D,
                                                   ln1_b + (l + 1) * D, nullptr, xb);
        } else {
            ln_kernel<false><<<L, 256, 0, stream>>>(h, lnf_w, lnf_b,
                                                    (float*)d_out, nullptr);
        }
    }
}

// Round 7
// 2013.201 us; speedup vs baseline: 1.0354x; 1.0354x over previous
//
#include <hip/hip_runtime.h>
#include <hip/hip_bf16.h>
#include <math.h>
#include <stdint.h>

#define L 2048
#define D 768
#define H 12
#define DH 64
#define F 3072
#define NL 12
#define QKVN 2304

typedef __attribute__((ext_vector_type(8))) short bf16x8;
typedef __attribute__((ext_vector_type(4))) float f32x4;

__device__ __forceinline__ ushort f2bf(float x) {
    union { float f; uint32_t u; } c; c.f = x;
    uint32_t r = c.u + 0x7FFFu + ((c.u >> 16) & 1u);
    return (ushort)(r >> 16);
}

// pack two f32 -> one dword of two bf16 (RNE)
__device__ __forceinline__ uint32_t cvt_pk_bf16(float lo, float hi) {
    uint32_t r;
    asm("v_cvt_pk_bf16_f32 %0, %1, %2" : "=v"(r) : "v"(lo), "v"(hi));
    return r;
}

__device__ __forceinline__ bf16x8 ldfrag(const ushort* p) {
    ushort4 lo = *(const ushort4*)(p);
    ushort4 hi = *(const ushort4*)(p + 16);
    bf16x8 f;
    f[0] = (short)lo.x; f[1] = (short)lo.y; f[2] = (short)lo.z; f[3] = (short)lo.w;
    f[4] = (short)hi.x; f[5] = (short)hi.y; f[6] = (short)hi.z; f[7] = (short)hi.w;
    return f;
}

__device__ __forceinline__ float gelu_tanh(float x) {
    float c = 0.7978845608028654f;
    float inner = c * (x + 0.044715f * x * x * x);
    return 0.5f * x * (1.0f + tanhf(inner));
}

// XCD-aware bijective swizzle of a linear workgroup id (valid when nwg % 8 == 0)
__device__ __forceinline__ int xcd_swz(int id, int nwg) {
    int cpx = nwg >> 3;
    return (id & 7) * cpx + (id >> 3);
}

// ---------------- position cumsum ----------------
__global__ void pos_kernel(const int* __restrict__ mask, int* __restrict__ pos) {
    __shared__ int sm[L];
    for (int i = threadIdx.x; i < L; i += blockDim.x) sm[i] = mask[i];
    __syncthreads();
    int t = blockIdx.x * blockDim.x + threadIdx.x;
    if (t < L) {
        int s = 0;
        for (int j = 0; j <= t; ++j) s += sm[j];
        int p = s - 1;
        if (sm[t] == 0) p = 1;
        pos[t] = p;
    }
}

__global__ void maskb_kernel(const int* __restrict__ mask, float* __restrict__ mb) {
    int i = blockIdx.x * blockDim.x + threadIdx.x;
    if (i < L) mb[i] = mask[i] ? 0.f : -1e9f;
}

// ---------------- embedding ----------------
__global__ __launch_bounds__(256) void embed_kernel(const int* __restrict__ ids,
                                                    const int* __restrict__ pos,
                                                    const float* __restrict__ wte,
                                                    const float* __restrict__ wpe,
                                                    float* __restrict__ h) {
    int t = blockIdx.x;
    int id = ids[t];
    int p = pos[t];
    const float* we = wte + (size_t)id * D;
    const float* wp = wpe + (size_t)p * D;
    float* hr = h + (size_t)t * D;
#pragma unroll
    for (int i = 0; i < 3; ++i) {
        int d = threadIdx.x + i * 256;
        hr[d] = we[d] + wp[d];
    }
}

// ---------------- layernorm (f32 in, bf16 or f32 out) ----------------
template <bool OUTBF>
__global__ __launch_bounds__(256) void ln_kernel(const float* __restrict__ in,
                                                 const float* __restrict__ w,
                                                 const float* __restrict__ b,
                                                 float* __restrict__ outF,
                                                 ushort* __restrict__ outB) {
    __shared__ float red[2][4];
    int row = blockIdx.x;
    const float* x = in + (size_t)row * D;
    int t = threadIdx.x;
    float v0 = x[t], v1 = x[t + 256], v2 = x[t + 512];
    float s = v0 + v1 + v2;
    float ss = v0 * v0 + v1 * v1 + v2 * v2;
#pragma unroll
    for (int o = 32; o; o >>= 1) {
        s += __shfl_xor(s, o);
        ss += __shfl_xor(ss, o);
    }
    int wave = t >> 6;
    if ((t & 63) == 0) { red[0][wave] = s; red[1][wave] = ss; }
    __syncthreads();
    s = red[0][0] + red[0][1] + red[0][2] + red[0][3];
    ss = red[1][0] + red[1][1] + red[1][2] + red[1][3];
    float mean = s * (1.f / D);
    float var = ss * (1.f / D) - mean * mean;
    float rstd = rsqrtf(var + 1e-5f);
#pragma unroll
    for (int i = 0; i < 3; ++i) {
        int d = t + i * 256;
        float vv = (i == 0) ? v0 : (i == 1) ? v1 : v2;
        float y = (vv - mean) * rstd * w[d] + b[d];
        if (OUTBF) outB[(size_t)row * D + d] = f2bf(y);
        else       outF[(size_t)row * D + d] = y;
    }
}

// ---------------- transpose-cast f32 [K][N] -> bf16 [N][K], z = layer ----------------
__global__ __launch_bounds__(256) void tcast_f32(const float* __restrict__ in,
                                                 ushort* __restrict__ out,
                                                 int K, int N,
                                                 size_t inStride, size_t outStride) {
    in += blockIdx.z * inStride;
    out += blockIdx.z * outStride;
    __shared__ float tile[64][65];
    int k0 = blockIdx.y * 64, n0 = blockIdx.x * 64;
    int t = threadIdx.x;
    int cl = t & 63, rg = t >> 6;
#pragma unroll
    for (int i = 0; i < 16; ++i) {
        int r = rg + 4 * i;
        tile[r][cl] = in[(size_t)(k0 + r) * N + n0 + cl];
    }
    __syncthreads();
#pragma unroll
    for (int i = 0; i < 16; ++i) {
        int r = rg + 4 * i;
        out[(size_t)(n0 + r) * K + k0 + cl] = f2bf(tile[cl][r]);
    }
}

// ---------------- bf16 MFMA GEMM, 128x128 tile, BK=32, dbuf, 1 barrier/step ----
// VSPLIT: for the QKV GEMM, cols >= 2*D (the V projection) are written
// transposed into vTout[(col-2D)*L + row] instead of outB.
template <int ACT, bool OUTBF, bool VSPLIT>
__global__ __launch_bounds__(256) void gemm_bf16(const ushort* __restrict__ A,
                                                 const ushort* __restrict__ Bt,
                                                 const float* __restrict__ bias,
                                                 const float* __restrict__ resid,
                                                 float* __restrict__ outF,
                                                 ushort* __restrict__ outB,
                                                 ushort* __restrict__ vTout,
                                                 int M, int N, int K) {
    __shared__ __align__(16) char lds[32768];   // 2 x (A 8K + B 8K)
    const int tid = threadIdx.x;
    const int lane = tid & 63, w = tid >> 6;
    const int wr = w >> 1, wc = w & 1;
    const int nwg = gridDim.x * gridDim.y;
    const int sid = xcd_swz(blockIdx.y * gridDim.x + blockIdx.x, nwg);
    const int bm = (sid / gridDim.x) * 128, bn = (sid % gridDim.x) * 128;
    const int l15 = lane & 15, l4 = lane >> 4;
    const int srow = tid >> 2, c = tid & 3;
    const int blo = (c & 1) * 32 + (c >> 1) * 8;

    const int sxor = (srow & 3) << 4;
    const int wo0 = srow * 64 + (blo ^ sxor);
    const int wo1 = srow * 64 + ((blo + 16) ^ sxor);
    const int rxor = (l4 * 16) ^ ((l15 & 3) << 4);
    const int aBase = (wr * 64 + l15) * 64 + rxor;
    const int bBase = (wc * 64 + l15) * 64 + rxor;

    f32x4 acc[4][4];
#pragma unroll
    for (int m = 0; m < 4; ++m)
#pragma unroll
        for (int n = 0; n < 4; ++n)
            acc[m][n] = (f32x4){0.f, 0.f, 0.f, 0.f};

    const ushort* Ag = A + (size_t)(bm + srow) * K + c * 8;
    const ushort* Ag2 = Ag + (size_t)64 * K;
    const ushort* Bg = Bt + (size_t)(bn + srow) * K + c * 8;
    const ushort* Bg2 = Bg + (size_t)64 * K;

    uint4 a0 = *(const uint4*)(Ag);
    uint4 a1 = *(const uint4*)(Ag2);
    uint4 b0 = *(const uint4*)(Bg);
    uint4 b1 = *(const uint4*)(Bg2);

    for (int k0 = 0; k0 < K; k0 += 32) {
        char* Ab = lds + ((k0 >> 5) & 1) * 16384;
        char* Bb = Ab + 8192;
        uint2 t0, t1;
        t0.x = a0.x; t0.y = a0.y; t1.x = a0.z; t1.y = a0.w;
        *(uint2*)(Ab + wo0) = t0;
        *(uint2*)(Ab + wo1) = t1;
        t0.x = a1.x; t0.y = a1.y; t1.x = a1.z; t1.y = a1.w;
        *(uint2*)(Ab + wo0 + 4096) = t0;
        *(uint2*)(Ab + wo1 + 4096) = t1;
        t0.x = b0.x; t0.y = b0.y; t1.x = b0.z; t1.y = b0.w;
        *(uint2*)(Bb + wo0) = t0;
        *(uint2*)(Bb + wo1) = t1;
        t0.x = b1.x; t0.y = b1.y; t1.x = b1.z; t1.y = b1.w;
        *(uint2*)(Bb + wo0 + 4096) = t0;
        *(uint2*)(Bb + wo1 + 4096) = t1;
        __syncthreads();
        if (k0 + 32 < K) {
            a0 = *(const uint4*)(Ag + k0 + 32);
            a1 = *(const uint4*)(Ag2 + k0 + 32);
            b0 = *(const uint4*)(Bg + k0 + 32);
            b1 = *(const uint4*)(Bg2 + k0 + 32);
        }
        bf16x8 af[4], bfv[4];
#pragma unroll
        for (int m = 0; m < 4; ++m)
            af[m] = *(const bf16x8*)(Ab + aBase + m * 1024);
#pragma unroll
        for (int n = 0; n < 4; ++n)
            bfv[n] = *(const bf16x8*)(Bb + bBase + n * 1024);
#pragma unroll
        for (int m = 0; m < 4; ++m)
#pragma unroll
            for (int n = 0; n < 4; ++n)
                acc[m][n] = __builtin_amdgcn_mfma_f32_16x16x32_bf16(af[m], bfv[n], acc[m][n], 0, 0, 0);
    }

#pragma unroll
    for (int m = 0; m < 4; ++m)
#pragma unroll
        for (int n = 0; n < 4; ++n) {
            int col = bn + wc * 64 + n * 16 + l15;
            int row0 = bm + wr * 64 + m * 16 + l4 * 4;
            if (VSPLIT && col >= 2 * D) {
                ushort4 pk;
                pk.x = f2bf(acc[m][n][0]);
                pk.y = f2bf(acc[m][n][1]);
                pk.z = f2bf(acc[m][n][2]);
                pk.w = f2bf(acc[m][n][3]);
                *(ushort4*)(vTout + (size_t)(col - 2 * D) * L + row0) = pk;
            } else {
#pragma unroll
                for (int r = 0; r < 4; ++r) {
                    int row = row0 + r;
                    float v = acc[m][n][r];
                    if (bias) v += bias[col];
                    if (ACT == 1) v = gelu_tanh(v);
                    if (resid) v += resid[(size_t)row * N + col];
                    if (OUTBF) outB[(size_t)row * N + col] = f2bf(v);
                    else       outF[(size_t)row * N + col] = v;
                }
            }
        }
}

// ---------------- bf16 MFMA GEMM, 64x64 tile, BK=64, dbuf, no split-K ----------
// For N=768 GEMMs (o-proj, pw). Epilogue fuses bias + residual into f32 h.
__global__ __launch_bounds__(256) void gemm64_bf16(const ushort* __restrict__ A,
                                                   const ushort* __restrict__ Bt,
                                                   const float* __restrict__ bias,
                                                   float* __restrict__ h,
                                                   int M, int N, int K) {
    __shared__ __align__(16) char lds[32768];   // 2 x (A 8K + B 8K)
    const int tid = threadIdx.x;
    const int lane = tid & 63, w = tid >> 6;
    const int wr = w >> 1, wc = w & 1;
    const int nwg = gridDim.x * gridDim.y;
    const int sid = xcd_swz(blockIdx.y * gridDim.x + blockIdx.x, nwg);
    const int bm = (sid / gridDim.x) * 64, bn = (sid % gridDim.x) * 64;
    const int l15 = lane & 15, l4 = lane >> 4;
    const int srow = tid >> 2, q = tid & 3;
    const int swz = (srow & 7) << 4;
    const int rb = srow * 128;
    int offlo[2], offhi[2];
#pragma unroll
    for (int i = 0; i < 2; ++i) {
        int g = 2 * q + i;
        int cc = g & 3, hf = g >> 2;
        int blo = (cc & 1) * 32 + ((cc >> 1) & 1) * 8 + hf * 64;
        offlo[i] = rb + ((blo & 0x70) ^ swz) + (blo & 15);
        int bhi = blo + 16;
        offhi[i] = rb + ((bhi & 0x70) ^ swz) + (bhi & 15);
    }
    const int fxor = (l15 & 7) << 4;

    f32x4 acc[2][2];
#pragma unroll
    for (int m = 0; m < 2; ++m)
#pragma unroll
        for (int n = 0; n < 2; ++n)
            acc[m][n] = (f32x4){0.f, 0.f, 0.f, 0.f};

    const ushort* Ag = A + (size_t)(bm + srow) * K + q * 16;
    const ushort* Bg = Bt + (size_t)(bn + srow) * K + q * 16;

    uint4 a0 = *(const uint4*)(Ag);
    uint4 a1 = *(const uint4*)(Ag + 8);
    uint4 b0 = *(const uint4*)(Bg);
    uint4 b1 = *(const uint4*)(Bg + 8);

    for (int k0 = 0; k0 < K; k0 += 64) {
        char* Ab = lds + ((k0 >> 6) & 1) * 16384;
        char* Bb = Ab + 8192;
        uint2 t0, t1;
        t0.x = a0.x; t0.y = a0.y; t1.x = a0.z; t1.y = a0.w;
        *(uint2*)(Ab + offlo[0]) = t0;
        *(uint2*)(Ab + offhi[0]) = t1;
        t0.x = a1.x; t0.y = a1.y; t1.x = a1.z; t1.y = a1.w;
        *(uint2*)(Ab + offlo[1]) = t0;
        *(uint2*)(Ab + offhi[1]) = t1;
        t0.x = b0.x; t0.y = b0.y; t1.x = b0.z; t1.y = b0.w;
        *(uint2*)(Bb + offlo[0]) = t0;
        *(uint2*)(Bb + offhi[0]) = t1;
        t0.x = b1.x; t0.y = b1.y; t1.x = b1.z; t1.y = b1.w;
        *(uint2*)(Bb + offlo[1]) = t0;
        *(uint2*)(Bb + offhi[1]) = t1;
        __syncthreads();
        if (k0 + 64 < K) {
            a0 = *(const uint4*)(Ag + k0 + 64);
            a1 = *(const uint4*)(Ag + k0 + 72);
            b0 = *(const uint4*)(Bg + k0 + 64);
            b1 = *(const uint4*)(Bg + k0 + 72);
        }
        bf16x8 af[2][2], bfv[2][2];
#pragma unroll
        for (int m = 0; m < 2; ++m)
#pragma unroll
            for (int ks = 0; ks < 2; ++ks)
                af[m][ks] = *(const bf16x8*)(Ab + (wr * 32 + m * 16 + l15) * 128 +
                                             ((ks * 64 + l4 * 16) ^ fxor));
#pragma unroll
        for (int n = 0; n < 2; ++n)
#pragma unroll
            for (int ks = 0; ks < 2; ++ks)
                bfv[n][ks] = *(const bf16x8*)(Bb + (wc * 32 + n * 16 + l15) * 128 +
                                              ((ks * 64 + l4 * 16) ^ fxor));
#pragma unroll
        for (int m = 0; m < 2; ++m)
#pragma unroll
            for (int n = 0; n < 2; ++n)
#pragma unroll
                for (int ks = 0; ks < 2; ++ks)
                    acc[m][n] = __builtin_amdgcn_mfma_f32_16x16x32_bf16(
                        af[m][ks], bfv[n][ks], acc[m][n], 0, 0, 0);
    }

#pragma unroll
    for (int m = 0; m < 2; ++m)
#pragma unroll
        for (int n = 0; n < 2; ++n) {
            int col = bn + wc * 32 + n * 16 + l15;
#pragma unroll
            for (int r = 0; r < 4; ++r) {
                int row = bm + wr * 32 + m * 16 + l4 * 4 + r;
                float v = acc[m][n][r] + bias[col] + h[(size_t)row * N + col];
                h[(size_t)row * N + col] = v;
            }
        }
}

// ---------------- MFMA flash attention, QBLK=64, 4 waves, KVBLK=64, dbuf ----
__global__ __launch_bounds__(256) void attn_kernel(const ushort* __restrict__ qkv,
                                                   const ushort* __restrict__ vT,
                                                   const float* __restrict__ maskb,
                                                   ushort* __restrict__ ctx) {
    __shared__ __align__(16) char Kl[2][8192];
    __shared__ __align__(16) char Vl[2][8192];
    __shared__ float Ml[2][64];
    const int hh = blockIdx.y;
    const int q0 = ((int)gridDim.x - 1 - (int)blockIdx.x) * 64;  // long blocks first
    const int tid = threadIdx.x;
    const int lane = tid & 63, w = tid >> 6;
    const int l15 = lane & 15, l4 = lane >> 4;
    const int qg = q0 + w * 16 + l15;
    const int qmin = q0 + w * 16;   // wave-uniform

    bf16x8 qf[2];
#pragma unroll
    for (int ks = 0; ks < 2; ++ks)
        qf[ks] = ldfrag(qkv + (size_t)qg * QKVN + hh * 64 + ks * 32 + l4 * 4);

    f32x4 o[4];
#pragma unroll
    for (int i = 0; i < 4; ++i) o[i] = (f32x4){0.f, 0.f, 0.f, 0.f};
    float mrun = -1e30f, lrun = 0.f;

    const int srow = tid >> 2, c = tid & 3;
    const int blo = (c & 1) * 32 + (c >> 1) * 8;
    const int swz = (srow & 7) << 4;
    const int rb = srow * 128;
    const int lo4 = blo & 15;
    const int s0 = rb + (((blo)      & 0x70) ^ swz) + lo4;
    const int s1 = rb + (((blo + 16) & 0x70) ^ swz) + lo4;
    const int s2 = rb + (((blo + 64) & 0x70) ^ swz) + lo4;
    const int s3 = rb + (((blo + 80) & 0x70) ^ swz) + lo4;
    const int fxor = (l15 & 7) << 4;

    const ushort* Ksrc = qkv + (size_t)srow * QKVN + D + hh * 64 + c * 8;
    const ushort* Vsrc = vT + (size_t)(hh * 64 + srow) * L + c * 8;

    uint4 ka, kb, va, vb;
    float mv = 0.f;
    const int nt = q0 / 64 + 1;

    {
        ka = *(const uint4*)(Ksrc);
        kb = *(const uint4*)(Ksrc + 32);
        va = *(const uint4*)(Vsrc);
        vb = *(const uint4*)(Vsrc + 32);
        if (tid < 64) mv = maskb[tid];
    }

    for (int it = 0; it < nt; ++it) {
        const int kv0 = it * 64;
        const int b = it & 1;
        {
            char* Kb = Kl[b];
            char* Vb = Vl[b];
            uint2 t0, t1;
            t0.x = ka.x; t0.y = ka.y; t1.x = ka.z; t1.y = ka.w;
            *(uint2*)(Kb + s0) = t0;
            *(uint2*)(Kb + s1) = t1;
            t0.x = kb.x; t0.y = kb.y; t1.x = kb.z; t1.y = kb.w;
            *(uint2*)(Kb + s2) = t0;
            *(uint2*)(Kb + s3) = t1;
            t0.x = va.x; t0.y = va.y; t1.x = va.z; t1.y = va.w;
            *(uint2*)(Vb + s0) = t0;
            *(uint2*)(Vb + s1) = t1;
            t0.x = vb.x; t0.y = vb.y; t1.x = vb.z; t1.y = vb.w;
            *(uint2*)(Vb + s2) = t0;
            *(uint2*)(Vb + s3) = t1;
            if (tid < 64) Ml[b][tid] = mv;
        }
        __syncthreads();
        if (it + 1 < nt) {
            const size_t koff = (size_t)(kv0 + 64) * QKVN;
            ka = *(const uint4*)(Ksrc + koff);
            kb = *(const uint4*)(Ksrc + koff + 32);
            va = *(const uint4*)(Vsrc + kv0 + 64);
            vb = *(const uint4*)(Vsrc + kv0 + 96);
            if (tid < 64) mv = maskb[kv0 + 64 + tid];
        }

        const char* Kb = Kl[b];
        const char* Vb = Vl[b];

        f32x4 st[4];
#pragma unroll
        for (int m = 0; m < 4; ++m) st[m] = (f32x4){0.f, 0.f, 0.f, 0.f};
#pragma unroll
        for (int m = 0; m < 4; ++m)
#pragma unroll
            for (int ks = 0; ks < 2; ++ks) {
                bf16x8 kf = *(const bf16x8*)(Kb + (m * 16 + l15) * 128 +
                                             ((ks * 64 + l4 * 16) ^ fxor));
                st[m] = __builtin_amdgcn_mfma_f32_16x16x32_bf16(kf, qf[ks], st[m], 0, 0, 0);
            }

        float p[4][4];
        float tmax = -1e30f;
        const bool full = (kv0 + 63 <= qmin);
        if (full) {
#pragma unroll
            for (int m = 0; m < 4; ++m)
#pragma unroll
                for (int r = 0; r < 4; ++r) {
                    int kl = m * 16 + l4 * 4 + r;
                    float s = st[m][r] + Ml[b][kl];
                    p[m][r] = s;
                    tmax = fmaxf(tmax, s);
                }
        } else {
#pragma unroll
            for (int m = 0; m < 4; ++m)
#pragma unroll
                for (int r = 0; r < 4; ++r) {
                    int kl = m * 16 + l4 * 4 + r;
                    float s = st[m][r] + Ml[b][kl];
                    if (kv0 + kl > qg) s = -1e30f;
                    p[m][r] = s;
                    tmax = fmaxf(tmax, s);
                }
        }
        tmax = fmaxf(tmax, __shfl_xor(tmax, 16));
        tmax = fmaxf(tmax, __shfl_xor(tmax, 32));
        const bool noresc = __all(tmax <= mrun);
        float mnew = noresc ? mrun : fmaxf(mrun, tmax);
        float scale = noresc ? 1.f : __expf(mrun - mnew);
        float ts = 0.f;
#pragma unroll
        for (int m = 0; m < 4; ++m)
#pragma unroll
            for (int r = 0; r < 4; ++r) {
                float e = __expf(p[m][r] - mnew);
                p[m][r] = e;
                ts += e;
            }
        ts += __shfl_xor(ts, 16);
        ts += __shfl_xor(ts, 32);
        lrun = lrun * scale + ts;
        mrun = mnew;

        bf16x8 pf[2];
#pragma unroll
        for (int g = 0; g < 2; ++g) {
            union { bf16x8 v; uint32_t d[4]; } pu;
            pu.d[0] = cvt_pk_bf16(p[2 * g][0], p[2 * g][1]);
            pu.d[1] = cvt_pk_bf16(p[2 * g][2], p[2 * g][3]);
            pu.d[2] = cvt_pk_bf16(p[2 * g + 1][0], p[2 * g + 1][1]);
            pu.d[3] = cvt_pk_bf16(p[2 * g + 1][2], p[2 * g + 1][3]);
            pf[g] = pu.v;
        }
        if (!noresc) {
#pragma unroll
            for (int i = 0; i < 4; ++i) {
                o[i][0] *= scale; o[i][1] *= scale; o[i][2] *= scale; o[i][3] *= scale;
            }
        }
#pragma unroll
        for (int dhb = 0; dhb < 4; ++dhb)
#pragma unroll
            for (int g = 0; g < 2; ++g) {
                bf16x8 vf = *(const bf16x8*)(Vb + (dhb * 16 + l15) * 128 +
                                             ((g * 64 + l4 * 16) ^ fxor));
                o[dhb] = __builtin_amdgcn_mfma_f32_16x16x32_bf16(vf, pf[g], o[dhb], 0, 0, 0);
            }
    }

    float rinv = 1.0f / lrun;
#pragma unroll
    for (int dhb = 0; dhb < 4; ++dhb) {
        ushort4 pk;
        pk.x = f2bf(o[dhb][0] * rinv);
        pk.y = f2bf(o[dhb][1] * rinv);
        pk.z = f2bf(o[dhb][2] * rinv);
        pk.w = f2bf(o[dhb][3] * rinv);
        *(ushort4*)(ctx + (size_t)qg * D + hh * 64 + dhb * 16 + l4 * 4) = pk;
    }
}

extern "C" void kernel_launch(void* const* d_in, const int* in_sizes, int n_in,
                              void* d_out, int out_size, void* d_ws, size_t ws_size,
                              hipStream_t stream) {
    const int* ids = (const int*)d_in[0];
    const int* amask = (const int*)d_in[1];
    const float* wte = (const float*)d_in[2];
    const float* wpe = (const float*)d_in[3];
    const float* lnf_w = (const float*)d_in[4];
    const float* lnf_b = (const float*)d_in[5];
    const float* ln1_w = (const float*)d_in[6];
    const float* ln1_b = (const float*)d_in[7];
    const float* qw = (const float*)d_in[8];
    const float* kw = (const float*)d_in[9];
    const float* vw = (const float*)d_in[10];
    const float* ow = (const float*)d_in[11];
    const float* ob = (const float*)d_in[12];
    const float* ln2_w = (const float*)d_in[13];
    const float* ln2_b = (const float*)d_in[14];
    const float* fcw = (const float*)d_in[15];
    const float* fcb = (const float*)d_in[16];
    const float* pw = (const float*)d_in[17];
    const float* pb = (const float*)d_in[18];

    char* p = (char*)d_ws;
    auto take = [&](size_t bytes) -> char* {
        char* r = p;
        p += (bytes + 4095) & ~(size_t)4095;
        return r;
    };
    ushort* wqkvT = (ushort*)take((size_t)NL * QKVN * D * 2);
    ushort* woT   = (ushort*)take((size_t)NL * D * D * 2);
    ushort* fcwT  = (ushort*)take((size_t)NL * F * D * 2);
    ushort* pwT   = (ushort*)take((size_t)NL * D * F * 2);
    float*  h     = (float*)take((size_t)L * D * 4);
    ushort* xb    = (ushort*)take((size_t)L * D * 2);
    ushort* qkvb  = (ushort*)take((size_t)L * QKVN * 2);
    ushort* vTb   = (ushort*)take((size_t)D * L * 2);
    ushort* ctxb  = (ushort*)take((size_t)L * D * 2);
    ushort* f1b   = (ushort*)take((size_t)L * F * 2);
    float*  mb    = (float*)take(L * 4);
    int*    pos   = (int*)take(L * 4);

    pos_kernel<<<8, 256, 0, stream>>>(amask, pos);
    maskb_kernel<<<8, 256, 0, stream>>>(amask, mb);
    embed_kernel<<<L, 256, 0, stream>>>(ids, pos, wte, wpe, h);

    tcast_f32<<<dim3(12, 12, NL), 256, 0, stream>>>(qw, wqkvT, D, D,
                                                    (size_t)D * D, (size_t)QKVN * D);
    tcast_f32<<<dim3(12, 12, NL), 256, 0, stream>>>(kw, wqkvT + (size_t)D * D, D, D,
                                                    (size_t)D * D, (size_t)QKVN * D);
    tcast_f32<<<dim3(12, 12, NL), 256, 0, stream>>>(vw, wqkvT + (size_t)2 * D * D, D, D,
                                                    (size_t)D * D, (size_t)QKVN * D);
    tcast_f32<<<dim3(12, 12, NL), 256, 0, stream>>>(ow, woT, D, D,
                                                    (size_t)D * D, (size_t)D * D);
    tcast_f32<<<dim3(48, 12, NL), 256, 0, stream>>>(fcw, fcwT, D, F,
                                                    (size_t)D * F, (size_t)F * D);
    tcast_f32<<<dim3(12, 48, NL), 256, 0, stream>>>(pw, pwT, F, D,
                                                    (size_t)F * D, (size_t)D * F);

    ln_kernel<true><<<L, 256, 0, stream>>>(h, ln1_w, ln1_b, nullptr, xb);

    for (int l = 0; l < NL; ++l) {
        gemm_bf16<0, true, true><<<dim3(QKVN / 128, L / 128), 256, 0, stream>>>(
            xb, wqkvT + (size_t)l * QKVN * D, nullptr, nullptr, nullptr, qkvb,
            vTb, L, QKVN, D);
        attn_kernel<<<dim3(L / 64, H), 256, 0, stream>>>(qkvb, vTb, mb, ctxb);
        gemm64_bf16<<<dim3(D / 64, L / 64), 256, 0, stream>>>(
            ctxb, woT + (size_t)l * D * D, ob + l * D, h, L, D, D);
        ln_kernel<true><<<L, 256, 0, stream>>>(h, ln2_w + l * D, ln2_b + l * D,
                                               nullptr, xb);
        gemm_bf16<1, true, false><<<dim3(F / 128, L / 128), 256, 0, stream>>>(
            xb, fcwT + (size_t)l * F * D, fcb + l * F, nullptr, nullptr, f1b,
            nullptr, L, F, D);
        gemm64_bf16<<<dim3(D / 64, L / 64), 256, 0, stream>>>(
            f1b, pwT + (size_t)l * D * F, pb + l * D, h, L, D, F);
        if (l < NL - 1) {
            ln_kernel<true><<<L, 256, 0, stream>>>(h, ln1_w + (l + 1) * D,
                                                   ln1_b + (l + 1) * D, nullptr, xb);
        } else {
            ln_kernel<false><<<L, 256, 0, stream>>>(h, lnf_w, lnf_b,
                                                    (float*)d_out, nullptr);
        }
    }
}

// Round 8
// 1824.937 us; speedup vs baseline: 1.1422x; 1.1032x over previous
//
#include <hip/hip_runtime.h>
#include <hip/hip_bf16.h>
#include <math.h>
#include <stdint.h>

#define L 2048
#define D 768
#define H 12
#define DH 64
#define F 3072
#define NL 12
#define QKVN 2304

typedef __attribute__((ext_vector_type(8))) short bf16x8;
typedef __attribute__((ext_vector_type(4))) float f32x4;

__device__ __forceinline__ ushort f2bf(float x) {
    union { float f; uint32_t u; } c; c.f = x;
    uint32_t r = c.u + 0x7FFFu + ((c.u >> 16) & 1u);
    return (ushort)(r >> 16);
}

// pack two f32 -> one dword of two bf16 (RNE)
__device__ __forceinline__ uint32_t cvt_pk_bf16(float lo, float hi) {
    uint32_t r;
    asm("v_cvt_pk_bf16_f32 %0, %1, %2" : "=v"(r) : "v"(lo), "v"(hi));
    return r;
}

__device__ __forceinline__ bf16x8 ldfrag(const ushort* p) {
    ushort4 lo = *(const ushort4*)(p);
    ushort4 hi = *(const ushort4*)(p + 16);
    bf16x8 f;
    f[0] = (short)lo.x; f[1] = (short)lo.y; f[2] = (short)lo.z; f[3] = (short)lo.w;
    f[4] = (short)hi.x; f[5] = (short)hi.y; f[6] = (short)hi.z; f[7] = (short)hi.w;
    return f;
}

__device__ __forceinline__ float gelu_tanh(float x) {
    float c = 0.7978845608028654f;
    float inner = c * (x + 0.044715f * x * x * x);
    return 0.5f * x * (1.0f + tanhf(inner));
}

// ---------------- position cumsum ----------------
__global__ void pos_kernel(const int* __restrict__ mask, int* __restrict__ pos) {
    __shared__ int sm[L];
    for (int i = threadIdx.x; i < L; i += blockDim.x) sm[i] = mask[i];
    __syncthreads();
    int t = blockIdx.x * blockDim.x + threadIdx.x;
    if (t < L) {
        int s = 0;
        for (int j = 0; j <= t; ++j) s += sm[j];
        int p = s - 1;
        if (sm[t] == 0) p = 1;
        pos[t] = p;
    }
}

__global__ void maskb_kernel(const int* __restrict__ mask, float* __restrict__ mb) {
    int i = blockIdx.x * blockDim.x + threadIdx.x;
    if (i < L) mb[i] = mask[i] ? 0.f : -1e9f;
}

// ---------------- embedding ----------------
__global__ __launch_bounds__(256) void embed_kernel(const int* __restrict__ ids,
                                                    const int* __restrict__ pos,
                                                    const float* __restrict__ wte,
                                                    const float* __restrict__ wpe,
                                                    float* __restrict__ h) {
    int t = blockIdx.x;
    int id = ids[t];
    int p = pos[t];
    const float* we = wte + (size_t)id * D;
    const float* wp = wpe + (size_t)p * D;
    float* hr = h + (size_t)t * D;
#pragma unroll
    for (int i = 0; i < 3; ++i) {
        int d = threadIdx.x + i * 256;
        hr[d] = we[d] + wp[d];
    }
}

// ---------------- layernorm (f32 in, bf16 out) ----------------
template <bool OUTBF>
__global__ __launch_bounds__(256) void ln_kernel(const float* __restrict__ in,
                                                 const float* __restrict__ w,
                                                 const float* __restrict__ b,
                                                 float* __restrict__ outF,
                                                 ushort* __restrict__ outB) {
    __shared__ float red[2][4];
    int row = blockIdx.x;
    const float* x = in + (size_t)row * D;
    int t = threadIdx.x;
    float v0 = x[t], v1 = x[t + 256], v2 = x[t + 512];
    float s = v0 + v1 + v2;
    float ss = v0 * v0 + v1 * v1 + v2 * v2;
#pragma unroll
    for (int o = 32; o; o >>= 1) {
        s += __shfl_xor(s, o);
        ss += __shfl_xor(ss, o);
    }
    int wave = t >> 6;
    if ((t & 63) == 0) { red[0][wave] = s; red[1][wave] = ss; }
    __syncthreads();
    s = red[0][0] + red[0][1] + red[0][2] + red[0][3];
    ss = red[1][0] + red[1][1] + red[1][2] + red[1][3];
    float mean = s * (1.f / D);
    float var = ss * (1.f / D) - mean * mean;
    float rstd = rsqrtf(var + 1e-5f);
#pragma unroll
    for (int i = 0; i < 3; ++i) {
        int d = t + i * 256;
        float vv = (i == 0) ? v0 : (i == 1) ? v1 : v2;
        float y = (vv - mean) * rstd * w[d] + b[d];
        if (OUTBF) outB[(size_t)row * D + d] = f2bf(y);
        else       outF[(size_t)row * D + d] = y;
    }
}

// ---- fused split-K reduce + bias + residual(h) + LayerNorm -> bf16 (or f32) ----
template <int S, bool OUTBF>
__global__ __launch_bounds__(256) void redln_kernel(const float* __restrict__ part,
                                                    const float* __restrict__ bias,
                                                    float* __restrict__ h,
                                                    const float* __restrict__ lnw,
                                                    const float* __restrict__ lnb,
                                                    ushort* __restrict__ outB,
                                                    float* __restrict__ outF) {
    __shared__ float red[2][4];
    int row = blockIdx.x;
    int t = threadIdx.x;
    float v[3];
    float s = 0.f, ss = 0.f;
#pragma unroll
    for (int i = 0; i < 3; ++i) {
        int d = t + i * 256;
        float x = h[(size_t)row * D + d] + bias[d];
#pragma unroll
        for (int sp = 0; sp < S; ++sp)
            x += part[((size_t)sp * L + row) * D + d];
        v[i] = x;
        h[(size_t)row * D + d] = x;
        s += x;
        ss += x * x;
    }
#pragma unroll
    for (int o = 32; o; o >>= 1) {
        s += __shfl_xor(s, o);
        ss += __shfl_xor(ss, o);
    }
    int wave = t >> 6;
    if ((t & 63) == 0) { red[0][wave] = s; red[1][wave] = ss; }
    __syncthreads();
    s = red[0][0] + red[0][1] + red[0][2] + red[0][3];
    ss = red[1][0] + red[1][1] + red[1][2] + red[1][3];
    float mean = s * (1.f / D);
    float var = ss * (1.f / D) - mean * mean;
    float rstd = rsqrtf(var + 1e-5f);
#pragma unroll
    for (int i = 0; i < 3; ++i) {
        int d = t + i * 256;
        float y = (v[i] - mean) * rstd * lnw[d] + lnb[d];
        if (OUTBF) outB[(size_t)row * D + d] = f2bf(y);
        else       outF[(size_t)row * D + d] = y;
    }
}

// ---------------- transpose-cast f32 [K][N] -> bf16 [N][K], z = layer ----------------
__global__ __launch_bounds__(256) void tcast_f32(const float* __restrict__ in,
                                                 ushort* __restrict__ out,
                                                 int K, int N,
                                                 size_t inStride, size_t outStride) {
    in += blockIdx.z * inStride;
    out += blockIdx.z * outStride;
    __shared__ float tile[64][65];
    int k0 = blockIdx.y * 64, n0 = blockIdx.x * 64;
    int t = threadIdx.x;
    int cl = t & 63, rg = t >> 6;
#pragma unroll
    for (int i = 0; i < 16; ++i) {
        int r = rg + 4 * i;
        tile[r][cl] = in[(size_t)(k0 + r) * N + n0 + cl];
    }
    __syncthreads();
#pragma unroll
    for (int i = 0; i < 16; ++i) {
        int r = rg + 4 * i;
        out[(size_t)(n0 + r) * K + k0 + cl] = f2bf(tile[cl][r]);
    }
}

// ---------------- bf16 MFMA GEMM, 128x128 tile, BK=32, dbuf, 1 barrier/step ----
// VSPLIT: for the QKV GEMM, cols >= 2*D (the V projection) are written
// transposed into vTout[(col-2D)*L + row] instead of outB.
// SPLITK>1: blockIdx.z = split over K, writes f32 partial to pout.
template <int ACT, bool OUTBF, int SPLITK, bool VSPLIT>
__global__ __launch_bounds__(256) void gemm_bf16(const ushort* __restrict__ A,
                                                 const ushort* __restrict__ Bt,
                                                 const float* __restrict__ bias,
                                                 const float* __restrict__ resid,
                                                 float* __restrict__ outF,
                                                 ushort* __restrict__ outB,
                                                 float* __restrict__ pout,
                                                 ushort* __restrict__ vTout,
                                                 int M, int N, int K) {
    __shared__ __align__(16) char lds[32768];   // 2 x (A 8K + B 8K)
    const int tid = threadIdx.x;
    const int lane = tid & 63, w = tid >> 6;
    const int wr = w >> 1, wc = w & 1;
    const int bm = blockIdx.y * 128, bn = blockIdx.x * 128;
    const int l15 = lane & 15, l4 = lane >> 4;
    const int srow = tid >> 2, c = tid & 3;
    const int blo = (c & 1) * 32 + (c >> 1) * 8;
    const int kLen = K / SPLITK;
    const int kStart = (SPLITK > 1) ? blockIdx.z * kLen : 0;

    const int sxor = (srow & 3) << 4;
    const int wo0 = srow * 64 + (blo ^ sxor);
    const int wo1 = srow * 64 + ((blo + 16) ^ sxor);
    const int rxor = (l4 * 16) ^ ((l15 & 3) << 4);
    const int aBase = (wr * 64 + l15) * 64 + rxor;
    const int bBase = (wc * 64 + l15) * 64 + rxor;

    f32x4 acc[4][4];
#pragma unroll
    for (int m = 0; m < 4; ++m)
#pragma unroll
        for (int n = 0; n < 4; ++n)
            acc[m][n] = (f32x4){0.f, 0.f, 0.f, 0.f};

    const ushort* Ag = A + (size_t)(bm + srow) * K + kStart + c * 8;
    const ushort* Ag2 = Ag + (size_t)64 * K;
    const ushort* Bg = Bt + (size_t)(bn + srow) * K + kStart + c * 8;
    const ushort* Bg2 = Bg + (size_t)64 * K;

    uint4 a0 = *(const uint4*)(Ag);
    uint4 a1 = *(const uint4*)(Ag2);
    uint4 b0 = *(const uint4*)(Bg);
    uint4 b1 = *(const uint4*)(Bg2);

    for (int k0 = 0; k0 < kLen; k0 += 32) {
        char* Ab = lds + ((k0 >> 5) & 1) * 16384;
        char* Bb = Ab + 8192;
        uint2 t0, t1;
        t0.x = a0.x; t0.y = a0.y; t1.x = a0.z; t1.y = a0.w;
        *(uint2*)(Ab + wo0) = t0;
        *(uint2*)(Ab + wo1) = t1;
        t0.x = a1.x; t0.y = a1.y; t1.x = a1.z; t1.y = a1.w;
        *(uint2*)(Ab + wo0 + 4096) = t0;
        *(uint2*)(Ab + wo1 + 4096) = t1;
        t0.x = b0.x; t0.y = b0.y; t1.x = b0.z; t1.y = b0.w;
        *(uint2*)(Bb + wo0) = t0;
        *(uint2*)(Bb + wo1) = t1;
        t0.x = b1.x; t0.y = b1.y; t1.x = b1.z; t1.y = b1.w;
        *(uint2*)(Bb + wo0 + 4096) = t0;
        *(uint2*)(Bb + wo1 + 4096) = t1;
        __syncthreads();
        if (k0 + 32 < kLen) {
            a0 = *(const uint4*)(Ag + k0 + 32);
            a1 = *(const uint4*)(Ag2 + k0 + 32);
            b0 = *(const uint4*)(Bg + k0 + 32);
            b1 = *(const uint4*)(Bg2 + k0 + 32);
        }
        bf16x8 af[4], bfv[4];
#pragma unroll
        for (int m = 0; m < 4; ++m)
            af[m] = *(const bf16x8*)(Ab + aBase + m * 1024);
#pragma unroll
        for (int n = 0; n < 4; ++n)
            bfv[n] = *(const bf16x8*)(Bb + bBase + n * 1024);
#pragma unroll
        for (int m = 0; m < 4; ++m)
#pragma unroll
            for (int n = 0; n < 4; ++n)
                acc[m][n] = __builtin_amdgcn_mfma_f32_16x16x32_bf16(af[m], bfv[n], acc[m][n], 0, 0, 0);
    }

    if (SPLITK > 1) {
        const size_t sb = (size_t)blockIdx.z * M;
#pragma unroll
        for (int m = 0; m < 4; ++m)
#pragma unroll
            for (int n = 0; n < 4; ++n) {
                int col = bn + wc * 64 + n * 16 + l15;
#pragma unroll
                for (int r = 0; r < 4; ++r) {
                    int row = bm + wr * 64 + m * 16 + l4 * 4 + r;
                    pout[(sb + row) * N + col] = acc[m][n][r];
                }
            }
    } else {
#pragma unroll
        for (int m = 0; m < 4; ++m)
#pragma unroll
            for (int n = 0; n < 4; ++n) {
                int col = bn + wc * 64 + n * 16 + l15;
                int row0 = bm + wr * 64 + m * 16 + l4 * 4;
                if (VSPLIT && col >= 2 * D) {
                    ushort4 pk;
                    pk.x = f2bf(acc[m][n][0]);
                    pk.y = f2bf(acc[m][n][1]);
                    pk.z = f2bf(acc[m][n][2]);
                    pk.w = f2bf(acc[m][n][3]);
                    *(ushort4*)(vTout + (size_t)(col - 2 * D) * L + row0) = pk;
                } else {
#pragma unroll
                    for (int r = 0; r < 4; ++r) {
                        int row = row0 + r;
                        float v = acc[m][n][r];
                        if (bias) v += bias[col];
                        if (ACT == 1) v = gelu_tanh(v);
                        if (resid) v += resid[(size_t)row * N + col];
                        if (OUTBF) outB[(size_t)row * N + col] = f2bf(v);
                        else       outF[(size_t)row * N + col] = v;
                    }
                }
            }
    }
}

// ------- MFMA flash attention, QBLK=64, KV-split over blockIdx.z, partials out ----
// Split s handles KV tiles [s*ceil(nt/NS), min(nt, ...)), emits f32 (o, m, l).
template <int NS>
__global__ __launch_bounds__(256) void attn_kernel(const ushort* __restrict__ qkv,
                                                   const ushort* __restrict__ vT,
                                                   const float* __restrict__ maskb,
                                                   float* __restrict__ po,
                                                   float* __restrict__ pm,
                                                   float* __restrict__ pl) {
    __shared__ __align__(16) char Kl[2][8192];
    __shared__ __align__(16) char Vl[2][8192];
    __shared__ float Ml[2][64];
    const int hh = blockIdx.y;
    const int sp = blockIdx.z;
    const int q0 = ((int)gridDim.x - 1 - (int)blockIdx.x) * 64;  // long blocks first
    const int tid = threadIdx.x;
    const int lane = tid & 63, w = tid >> 6;
    const int l15 = lane & 15, l4 = lane >> 4;
    const int qg = q0 + w * 16 + l15;
    const int qmin = q0 + w * 16;   // wave-uniform

    const int nt = q0 / 64 + 1;
    const int chunk = (nt + NS - 1) / NS;
    const int it0 = sp * chunk;
    int it1 = it0 + chunk;
    if (it1 > nt) it1 = nt;

    f32x4 o[4];
#pragma unroll
    for (int i = 0; i < 4; ++i) o[i] = (f32x4){0.f, 0.f, 0.f, 0.f};
    float mrun = -1e30f, lrun = 0.f;

    if (it0 < it1) {
        bf16x8 qf[2];
#pragma unroll
        for (int ks = 0; ks < 2; ++ks)
            qf[ks] = ldfrag(qkv + (size_t)qg * QKVN + hh * 64 + ks * 32 + l4 * 4);

        const int srow = tid >> 2, c = tid & 3;
        const int blo = (c & 1) * 32 + (c >> 1) * 8;
        const int swz = (srow & 7) << 4;
        const int rb = srow * 128;
        const int lo4 = blo & 15;
        const int s0 = rb + (((blo)      & 0x70) ^ swz) + lo4;
        const int s1 = rb + (((blo + 16) & 0x70) ^ swz) + lo4;
        const int s2 = rb + (((blo + 64) & 0x70) ^ swz) + lo4;
        const int s3 = rb + (((blo + 80) & 0x70) ^ swz) + lo4;
        const int fxor = (l15 & 7) << 4;

        const ushort* Ksrc = qkv + (size_t)srow * QKVN + D + hh * 64 + c * 8;
        const ushort* Vsrc = vT + (size_t)(hh * 64 + srow) * L + c * 8;

        uint4 ka, kb, va, vb;
        float mv = 0.f;
        {
            const size_t koff = (size_t)(it0 * 64) * QKVN;
            ka = *(const uint4*)(Ksrc + koff);
            kb = *(const uint4*)(Ksrc + koff + 32);
            va = *(const uint4*)(Vsrc + it0 * 64);
            vb = *(const uint4*)(Vsrc + it0 * 64 + 32);
            if (tid < 64) mv = maskb[it0 * 64 + tid];
        }

        for (int it = it0; it < it1; ++it) {
            const int kv0 = it * 64;
            const int b = it & 1;
            {
                char* Kb = Kl[b];
                char* Vb = Vl[b];
                uint2 t0, t1;
                t0.x = ka.x; t0.y = ka.y; t1.x = ka.z; t1.y = ka.w;
                *(uint2*)(Kb + s0) = t0;
                *(uint2*)(Kb + s1) = t1;
                t0.x = kb.x; t0.y = kb.y; t1.x = kb.z; t1.y = kb.w;
                *(uint2*)(Kb + s2) = t0;
                *(uint2*)(Kb + s3) = t1;
                t0.x = va.x; t0.y = va.y; t1.x = va.z; t1.y = va.w;
                *(uint2*)(Vb + s0) = t0;
                *(uint2*)(Vb + s1) = t1;
                t0.x = vb.x; t0.y = vb.y; t1.x = vb.z; t1.y = vb.w;
                *(uint2*)(Vb + s2) = t0;
                *(uint2*)(Vb + s3) = t1;
                if (tid < 64) Ml[b][tid] = mv;
            }
            __syncthreads();
            if (it + 1 < it1) {
                const size_t koff = (size_t)(kv0 + 64) * QKVN;
                ka = *(const uint4*)(Ksrc + koff);
                kb = *(const uint4*)(Ksrc + koff + 32);
                va = *(const uint4*)(Vsrc + kv0 + 64);
                vb = *(const uint4*)(Vsrc + kv0 + 96);
                if (tid < 64) mv = maskb[kv0 + 64 + tid];
            }

            const char* Kb = Kl[b];
            const char* Vb = Vl[b];

            f32x4 st[4];
#pragma unroll
            for (int m = 0; m < 4; ++m) st[m] = (f32x4){0.f, 0.f, 0.f, 0.f};
#pragma unroll
            for (int m = 0; m < 4; ++m)
#pragma unroll
                for (int ks = 0; ks < 2; ++ks) {
                    bf16x8 kf = *(const bf16x8*)(Kb + (m * 16 + l15) * 128 +
                                                 ((ks * 64 + l4 * 16) ^ fxor));
                    st[m] = __builtin_amdgcn_mfma_f32_16x16x32_bf16(kf, qf[ks], st[m], 0, 0, 0);
                }

            float p[4][4];
            float tmax = -1e30f;
            const bool full = (kv0 + 63 <= qmin);
            if (full) {
#pragma unroll
                for (int m = 0; m < 4; ++m)
#pragma unroll
                    for (int r = 0; r < 4; ++r) {
                        int kl = m * 16 + l4 * 4 + r;
                        float s = st[m][r] + Ml[b][kl];
                        p[m][r] = s;
                        tmax = fmaxf(tmax, s);
                    }
            } else {
#pragma unroll
                for (int m = 0; m < 4; ++m)
#pragma unroll
                    for (int r = 0; r < 4; ++r) {
                        int kl = m * 16 + l4 * 4 + r;
                        float s = st[m][r] + Ml[b][kl];
                        if (kv0 + kl > qg) s = -1e30f;
                        p[m][r] = s;
                        tmax = fmaxf(tmax, s);
                    }
            }
            tmax = fmaxf(tmax, __shfl_xor(tmax, 16));
            tmax = fmaxf(tmax, __shfl_xor(tmax, 32));
            const bool noresc = __all(tmax <= mrun);
            float mnew = noresc ? mrun : fmaxf(mrun, tmax);
            float scale = noresc ? 1.f : __expf(mrun - mnew);
            float ts = 0.f;
#pragma unroll
            for (int m = 0; m < 4; ++m)
#pragma unroll
                for (int r = 0; r < 4; ++r) {
                    float e = __expf(p[m][r] - mnew);
                    p[m][r] = e;
                    ts += e;
                }
            ts += __shfl_xor(ts, 16);
            ts += __shfl_xor(ts, 32);
            lrun = lrun * scale + ts;
            mrun = mnew;

            bf16x8 pf[2];
#pragma unroll
            for (int g = 0; g < 2; ++g) {
                union { bf16x8 v; uint32_t d[4]; } pu;
                pu.d[0] = cvt_pk_bf16(p[2 * g][0], p[2 * g][1]);
                pu.d[1] = cvt_pk_bf16(p[2 * g][2], p[2 * g][3]);
                pu.d[2] = cvt_pk_bf16(p[2 * g + 1][0], p[2 * g + 1][1]);
                pu.d[3] = cvt_pk_bf16(p[2 * g + 1][2], p[2 * g + 1][3]);
                pf[g] = pu.v;
            }
            if (!noresc) {
#pragma unroll
                for (int i = 0; i < 4; ++i) {
                    o[i][0] *= scale; o[i][1] *= scale; o[i][2] *= scale; o[i][3] *= scale;
                }
            }
#pragma unroll
            for (int dhb = 0; dhb < 4; ++dhb)
#pragma unroll
                for (int g = 0; g < 2; ++g) {
                    bf16x8 vf = *(const bf16x8*)(Vb + (dhb * 16 + l15) * 128 +
                                                 ((g * 64 + l4 * 16) ^ fxor));
                    o[dhb] = __builtin_amdgcn_mfma_f32_16x16x32_bf16(vf, pf[g], o[dhb], 0, 0, 0);
                }
        }
    }

    // write partials (o f32, m, l)
    const size_t pb = (size_t)(sp * H + hh) * L + qg;
    if (l4 == 0) { pm[pb] = mrun; pl[pb] = lrun; }
    float* op = po + pb * 64;
#pragma unroll
    for (int dhb = 0; dhb < 4; ++dhb)
        *(f32x4*)(op + dhb * 16 + l4 * 4) = o[dhb];
}

// ---------------- flash combine: merge NS partials -> bf16 ctx ----------------
template <int NS>
__global__ __launch_bounds__(256) void attn_combine(const float* __restrict__ po,
                                                    const float* __restrict__ pm,
                                                    const float* __restrict__ pl,
                                                    ushort* __restrict__ ctx) {
    const int hh = blockIdx.y;
    const int q = blockIdx.x * 64 + (threadIdx.x >> 2);
    const int d0 = (threadIdx.x & 3) * 16;
    size_t idx[NS];
    float mm = -1e30f;
#pragma unroll
    for (int s = 0; s < NS; ++s) {
        idx[s] = (size_t)(s * H + hh) * L + q;
        mm = fmaxf(mm, pm[idx[s]]);
    }
    float e[NS];
    float l = 0.f;
#pragma unroll
    for (int s = 0; s < NS; ++s) {
        e[s] = __expf(pm[idx[s]] - mm);
        l += pl[idx[s]] * e[s];
    }
    float rinv = 1.0f / l;
    ushort* cp = ctx + (size_t)q * D + hh * 64 + d0;
#pragma unroll
    for (int j = 0; j < 16; j += 4) {
        float acc[4] = {0.f, 0.f, 0.f, 0.f};
#pragma unroll
        for (int s = 0; s < NS; ++s) {
            const float* op = po + idx[s] * 64 + d0 + j;
            float4 v = *(const float4*)op;
            acc[0] += v.x * e[s];
            acc[1] += v.y * e[s];
            acc[2] += v.z * e[s];
            acc[3] += v.w * e[s];
        }
        ushort4 pk;
        pk.x = f2bf(acc[0] * rinv);
        pk.y = f2bf(acc[1] * rinv);
        pk.z = f2bf(acc[2] * rinv);
        pk.w = f2bf(acc[3] * rinv);
        *(ushort4*)(cp + j) = pk;
    }
}

extern "C" void kernel_launch(void* const* d_in, const int* in_sizes, int n_in,
                              void* d_out, int out_size, void* d_ws, size_t ws_size,
                              hipStream_t stream) {
    const int* ids = (const int*)d_in[0];
    const int* amask = (const int*)d_in[1];
    const float* wte = (const float*)d_in[2];
    const float* wpe = (const float*)d_in[3];
    const float* lnf_w = (const float*)d_in[4];
    const float* lnf_b = (const float*)d_in[5];
    const float* ln1_w = (const float*)d_in[6];
    const float* ln1_b = (const float*)d_in[7];
    const float* qw = (const float*)d_in[8];
    const float* kw = (const float*)d_in[9];
    const float* vw = (const float*)d_in[10];
    const float* ow = (const float*)d_in[11];
    const float* ob = (const float*)d_in[12];
    const float* ln2_w = (const float*)d_in[13];
    const float* ln2_b = (const float*)d_in[14];
    const float* fcw = (const float*)d_in[15];
    const float* fcb = (const float*)d_in[16];
    const float* pw = (const float*)d_in[17];
    const float* pb = (const float*)d_in[18];

    char* p = (char*)d_ws;
    auto take = [&](size_t bytes) -> char* {
        char* r = p;
        p += (bytes + 4095) & ~(size_t)4095;
        return r;
    };
    ushort* wqkvT = (ushort*)take((size_t)NL * QKVN * D * 2);
    ushort* woT   = (ushort*)take((size_t)NL * D * D * 2);
    ushort* fcwT  = (ushort*)take((size_t)NL * F * D * 2);
    ushort* pwT   = (ushort*)take((size_t)NL * D * F * 2);
    float*  h     = (float*)take((size_t)L * D * 4);
    ushort* xb    = (ushort*)take((size_t)L * D * 2);
    ushort* qkvb  = (ushort*)take((size_t)L * QKVN * 2);
    ushort* vTb   = (ushort*)take((size_t)D * L * 2);
    ushort* ctxb  = (ushort*)take((size_t)L * D * 2);
    ushort* f1b   = (ushort*)take((size_t)L * F * 2);
    float*  pk    = (float*)take((size_t)4 * L * D * 4);     // split-K partials
    float*  po    = (float*)take((size_t)2 * H * L * 64 * 4); // attn o partials
    float*  pm    = (float*)take((size_t)2 * H * L * 4);
    float*  pl    = (float*)take((size_t)2 * H * L * 4);
    float*  mb    = (float*)take(L * 4);
    int*    pos   = (int*)take(L * 4);

    pos_kernel<<<8, 256, 0, stream>>>(amask, pos);
    maskb_kernel<<<8, 256, 0, stream>>>(amask, mb);
    embed_kernel<<<L, 256, 0, stream>>>(ids, pos, wte, wpe, h);

    tcast_f32<<<dim3(12, 12, NL), 256, 0, stream>>>(qw, wqkvT, D, D,
                                                    (size_t)D * D, (size_t)QKVN * D);
    tcast_f32<<<dim3(12, 12, NL), 256, 0, stream>>>(kw, wqkvT + (size_t)D * D, D, D,
                                                    (size_t)D * D, (size_t)QKVN * D);
    tcast_f32<<<dim3(12, 12, NL), 256, 0, stream>>>(vw, wqkvT + (size_t)2 * D * D, D, D,
                                                    (size_t)D * D, (size_t)QKVN * D);
    tcast_f32<<<dim3(12, 12, NL), 256, 0, stream>>>(ow, woT, D, D,
                                                    (size_t)D * D, (size_t)D * D);
    tcast_f32<<<dim3(48, 12, NL), 256, 0, stream>>>(fcw, fcwT, D, F,
                                                    (size_t)D * F, (size_t)F * D);
    tcast_f32<<<dim3(12, 48, NL), 256, 0, stream>>>(pw, pwT, F, D,
                                                    (size_t)F * D, (size_t)D * F);

    ln_kernel<true><<<L, 256, 0, stream>>>(h, ln1_w, ln1_b, nullptr, xb);

    for (int l = 0; l < NL; ++l) {
        gemm_bf16<0, true, 1, true><<<dim3(QKVN / 128, L / 128), 256, 0, stream>>>(
            xb, wqkvT + (size_t)l * QKVN * D, nullptr, nullptr, nullptr, qkvb, nullptr,
            vTb, L, QKVN, D);
        attn_kernel<2><<<dim3(L / 64, H, 2), 256, 0, stream>>>(qkvb, vTb, mb,
                                                               po, pm, pl);
        attn_combine<2><<<dim3(L / 64, H), 256, 0, stream>>>(po, pm, pl, ctxb);
        gemm_bf16<0, true, 4, false><<<dim3(D / 128, L / 128, 4), 256, 0, stream>>>(
            ctxb, woT + (size_t)l * D * D, nullptr, nullptr, nullptr, nullptr, pk,
            nullptr, L, D, D);
        redln_kernel<4, true><<<L, 256, 0, stream>>>(
            pk, ob + l * D, h, ln2_w + l * D, ln2_b + l * D, xb, nullptr);
        gemm_bf16<1, true, 1, false><<<dim3(F / 128, L / 128), 256, 0, stream>>>(
            xb, fcwT + (size_t)l * F * D, fcb + l * F, nullptr, nullptr, f1b, nullptr,
            nullptr, L, F, D);
        gemm_bf16<0, true, 4, false><<<dim3(D / 128, L / 128, 4), 256, 0, stream>>>(
            f1b, pwT + (size_t)l * D * F, nullptr, nullptr, nullptr, nullptr, pk,
            nullptr, L, D, F);
        if (l < NL - 1) {
            redln_kernel<4, true><<<L, 256, 0, stream>>>(
                pk, pb + l * D, h, ln1_w + (l + 1) * D, ln1_b + (l + 1) * D, xb, nullptr);
        } else {
            redln_kernel<4, false><<<L, 256, 0, stream>>>(
                pk, pb + l * D, h, lnf_w, lnf_b, nullptr, (float*)d_out);
        }
    }
}

// Round 9
// 1808.009 us; speedup vs baseline: 1.1529x; 1.0094x over previous
//
#include <hip/hip_runtime.h>
#include <hip/hip_bf16.h>
#include <math.h>
#include <stdint.h>

#define L 2048
#define D 768
#define H 12
#define DH 64
#define F 3072
#define NL 12
#define QKVN 2304

typedef __attribute__((ext_vector_type(8))) short bf16x8;
typedef __attribute__((ext_vector_type(4))) float f32x4;

__device__ __forceinline__ ushort f2bf(float x) {
    union { float f; uint32_t u; } c; c.f = x;
    uint32_t r = c.u + 0x7FFFu + ((c.u >> 16) & 1u);
    return (ushort)(r >> 16);
}

// pack two f32 -> one dword of two bf16 (RNE)
__device__ __forceinline__ uint32_t cvt_pk_bf16(float lo, float hi) {
    uint32_t r;
    asm("v_cvt_pk_bf16_f32 %0, %1, %2" : "=v"(r) : "v"(lo), "v"(hi));
    return r;
}

__device__ __forceinline__ bf16x8 ldfrag(const ushort* p) {
    ushort4 lo = *(const ushort4*)(p);
    ushort4 hi = *(const ushort4*)(p + 16);
    bf16x8 f;
    f[0] = (short)lo.x; f[1] = (short)lo.y; f[2] = (short)lo.z; f[3] = (short)lo.w;
    f[4] = (short)hi.x; f[5] = (short)hi.y; f[6] = (short)hi.z; f[7] = (short)hi.w;
    return f;
}

__device__ __forceinline__ float gelu_tanh(float x) {
    float c = 0.7978845608028654f;
    float inner = c * (x + 0.044715f * x * x * x);
    return 0.5f * x * (1.0f + tanhf(inner));
}

// ---------------- position cumsum ----------------
__global__ void pos_kernel(const int* __restrict__ mask, int* __restrict__ pos) {
    __shared__ int sm[L];
    for (int i = threadIdx.x; i < L; i += blockDim.x) sm[i] = mask[i];
    __syncthreads();
    int t = blockIdx.x * blockDim.x + threadIdx.x;
    if (t < L) {
        int s = 0;
        for (int j = 0; j <= t; ++j) s += sm[j];
        int p = s - 1;
        if (sm[t] == 0) p = 1;
        pos[t] = p;
    }
}

__global__ void maskb_kernel(const int* __restrict__ mask, float* __restrict__ mb) {
    int i = blockIdx.x * blockDim.x + threadIdx.x;
    if (i < L) mb[i] = mask[i] ? 0.f : -1e9f;
}

// ---------------- embedding ----------------
__global__ __launch_bounds__(256) void embed_kernel(const int* __restrict__ ids,
                                                    const int* __restrict__ pos,
                                                    const float* __restrict__ wte,
                                                    const float* __restrict__ wpe,
                                                    float* __restrict__ h) {
    int t = blockIdx.x;
    int id = ids[t];
    int p = pos[t];
    const float* we = wte + (size_t)id * D;
    const float* wp = wpe + (size_t)p * D;
    float* hr = h + (size_t)t * D;
#pragma unroll
    for (int i = 0; i < 3; ++i) {
        int d = threadIdx.x + i * 256;
        hr[d] = we[d] + wp[d];
    }
}

// ---------------- layernorm (f32 in, bf16 out) ----------------
template <bool OUTBF>
__global__ __launch_bounds__(256) void ln_kernel(const float* __restrict__ in,
                                                 const float* __restrict__ w,
                                                 const float* __restrict__ b,
                                                 float* __restrict__ outF,
                                                 ushort* __restrict__ outB) {
    __shared__ float red[2][4];
    int row = blockIdx.x;
    const float* x = in + (size_t)row * D;
    int t = threadIdx.x;
    float v0 = x[t], v1 = x[t + 256], v2 = x[t + 512];
    float s = v0 + v1 + v2;
    float ss = v0 * v0 + v1 * v1 + v2 * v2;
#pragma unroll
    for (int o = 32; o; o >>= 1) {
        s += __shfl_xor(s, o);
        ss += __shfl_xor(ss, o);
    }
    int wave = t >> 6;
    if ((t & 63) == 0) { red[0][wave] = s; red[1][wave] = ss; }
    __syncthreads();
    s = red[0][0] + red[0][1] + red[0][2] + red[0][3];
    ss = red[1][0] + red[1][1] + red[1][2] + red[1][3];
    float mean = s * (1.f / D);
    float var = ss * (1.f / D) - mean * mean;
    float rstd = rsqrtf(var + 1e-5f);
#pragma unroll
    for (int i = 0; i < 3; ++i) {
        int d = t + i * 256;
        float vv = (i == 0) ? v0 : (i == 1) ? v1 : v2;
        float y = (vv - mean) * rstd * w[d] + b[d];
        if (OUTBF) outB[(size_t)row * D + d] = f2bf(y);
        else       outF[(size_t)row * D + d] = y;
    }
}

// ---- fused split-K reduce + bias + residual(h) + LayerNorm -> bf16 (or f32) ----
template <int S, bool OUTBF>
__global__ __launch_bounds__(256) void redln_kernel(const float* __restrict__ part,
                                                    const float* __restrict__ bias,
                                                    float* __restrict__ h,
                                                    const float* __restrict__ lnw,
                                                    const float* __restrict__ lnb,
                                                    ushort* __restrict__ outB,
                                                    float* __restrict__ outF) {
    __shared__ float red[2][4];
    int row = blockIdx.x;
    int t = threadIdx.x;
    float v[3];
    float s = 0.f, ss = 0.f;
#pragma unroll
    for (int i = 0; i < 3; ++i) {
        int d = t + i * 256;
        float x = h[(size_t)row * D + d] + bias[d];
#pragma unroll
        for (int sp = 0; sp < S; ++sp)
            x += part[((size_t)sp * L + row) * D + d];
        v[i] = x;
        h[(size_t)row * D + d] = x;
        s += x;
        ss += x * x;
    }
#pragma unroll
    for (int o = 32; o; o >>= 1) {
        s += __shfl_xor(s, o);
        ss += __shfl_xor(ss, o);
    }
    int wave = t >> 6;
    if ((t & 63) == 0) { red[0][wave] = s; red[1][wave] = ss; }
    __syncthreads();
    s = red[0][0] + red[0][1] + red[0][2] + red[0][3];
    ss = red[1][0] + red[1][1] + red[1][2] + red[1][3];
    float mean = s * (1.f / D);
    float var = ss * (1.f / D) - mean * mean;
    float rstd = rsqrtf(var + 1e-5f);
#pragma unroll
    for (int i = 0; i < 3; ++i) {
        int d = t + i * 256;
        float y = (v[i] - mean) * rstd * lnw[d] + lnb[d];
        if (OUTBF) outB[(size_t)row * D + d] = f2bf(y);
        else       outF[(size_t)row * D + d] = y;
    }
}

// ---------------- transpose-cast f32 [K][N] -> bf16 [N][K], z = layer ----------------
__global__ __launch_bounds__(256) void tcast_f32(const float* __restrict__ in,
                                                 ushort* __restrict__ out,
                                                 int K, int N,
                                                 size_t inStride, size_t outStride) {
    in += blockIdx.z * inStride;
    out += blockIdx.z * outStride;
    __shared__ float tile[64][65];
    int k0 = blockIdx.y * 64, n0 = blockIdx.x * 64;
    int t = threadIdx.x;
    int cl = t & 63, rg = t >> 6;
#pragma unroll
    for (int i = 0; i < 16; ++i) {
        int r = rg + 4 * i;
        tile[r][cl] = in[(size_t)(k0 + r) * N + n0 + cl];
    }
    __syncthreads();
#pragma unroll
    for (int i = 0; i < 16; ++i) {
        int r = rg + 4 * i;
        out[(size_t)(n0 + r) * K + k0 + cl] = f2bf(tile[cl][r]);
    }
}

// ---------------- bf16 MFMA GEMM, 128x128 tile, BK=32, dbuf LDS, depth-2 prefetch ----
// One barrier per K-step; global loads issued TWO steps ahead (two named reg
// sets, loop unrolled x2 — kLen must be a multiple of 64, true for all uses).
// VSPLIT: for the QKV GEMM, cols >= 2*D (the V projection) are written
// transposed into vTout[(col-2D)*L + row] instead of outB.
// SPLITK>1: blockIdx.z = split over K, writes f32 partial to pout.
template <int ACT, bool OUTBF, int SPLITK, bool VSPLIT>
__global__ __launch_bounds__(256) void gemm_bf16(const ushort* __restrict__ A,
                                                 const ushort* __restrict__ Bt,
                                                 const float* __restrict__ bias,
                                                 const float* __restrict__ resid,
                                                 float* __restrict__ outF,
                                                 ushort* __restrict__ outB,
                                                 float* __restrict__ pout,
                                                 ushort* __restrict__ vTout,
                                                 int M, int N, int K) {
    __shared__ __align__(16) char lds[32768];   // 2 x (A 8K + B 8K)
    const int tid = threadIdx.x;
    const int lane = tid & 63, w = tid >> 6;
    const int wr = w >> 1, wc = w & 1;
    const int bm = blockIdx.y * 128, bn = blockIdx.x * 128;
    const int l15 = lane & 15, l4 = lane >> 4;
    const int srow = tid >> 2, c = tid & 3;
    const int blo = (c & 1) * 32 + (c >> 1) * 8;
    const int kLen = K / SPLITK;
    const int kStart = (SPLITK > 1) ? blockIdx.z * kLen : 0;

    const int sxor = (srow & 3) << 4;
    const int wo0 = srow * 64 + (blo ^ sxor);
    const int wo1 = srow * 64 + ((blo + 16) ^ sxor);
    const int rxor = (l4 * 16) ^ ((l15 & 3) << 4);
    const int aBase = (wr * 64 + l15) * 64 + rxor;
    const int bBase = (wc * 64 + l15) * 64 + rxor;

    f32x4 acc[4][4];
#pragma unroll
    for (int m = 0; m < 4; ++m)
#pragma unroll
        for (int n = 0; n < 4; ++n)
            acc[m][n] = (f32x4){0.f, 0.f, 0.f, 0.f};

    const ushort* Ag = A + (size_t)(bm + srow) * K + kStart + c * 8;
    const ushort* Ag2 = Ag + (size_t)64 * K;
    const ushort* Bg = Bt + (size_t)(bn + srow) * K + kStart + c * 8;
    const ushort* Bg2 = Bg + (size_t)64 * K;

    // two staging register sets, loaded 2 steps ahead
    uint4 xa0, xa1, xb0, xb1;   // set X (even steps)
    uint4 ya0, ya1, yb0, yb1;   // set Y (odd steps)
    xa0 = *(const uint4*)(Ag);
    xa1 = *(const uint4*)(Ag2);
    xb0 = *(const uint4*)(Bg);
    xb1 = *(const uint4*)(Bg2);
    ya0 = *(const uint4*)(Ag + 32);
    ya1 = *(const uint4*)(Ag2 + 32);
    yb0 = *(const uint4*)(Bg + 32);
    yb1 = *(const uint4*)(Bg2 + 32);

#define GSTAGE_WRITE(BUF, A0, A1, B0, B1)                     \
    {                                                          \
        char* Ab_ = lds + (BUF) * 16384;                       \
        char* Bb_ = Ab_ + 8192;                                \
        uint2 t0, t1;                                          \
        t0.x = A0.x; t0.y = A0.y; t1.x = A0.z; t1.y = A0.w;    \
        *(uint2*)(Ab_ + wo0) = t0;                             \
        *(uint2*)(Ab_ + wo1) = t1;                             \
        t0.x = A1.x; t0.y = A1.y; t1.x = A1.z; t1.y = A1.w;    \
        *(uint2*)(Ab_ + wo0 + 4096) = t0;                      \
        *(uint2*)(Ab_ + wo1 + 4096) = t1;                      \
        t0.x = B0.x; t0.y = B0.y; t1.x = B0.z; t1.y = B0.w;    \
        *(uint2*)(Bb_ + wo0) = t0;                             \
        *(uint2*)(Bb_ + wo1) = t1;                             \
        t0.x = B1.x; t0.y = B1.y; t1.x = B1.z; t1.y = B1.w;    \
        *(uint2*)(Bb_ + wo0 + 4096) = t0;                      \
        *(uint2*)(Bb_ + wo1 + 4096) = t1;                      \
    }

#define GCOMPUTE(BUF)                                                     \
    {                                                                      \
        char* Ab_ = lds + (BUF) * 16384;                                   \
        char* Bb_ = Ab_ + 8192;                                            \
        bf16x8 af[4], bfv[4];                                              \
        _Pragma("unroll")                                                  \
        for (int m = 0; m < 4; ++m)                                        \
            af[m] = *(const bf16x8*)(Ab_ + aBase + m * 1024);              \
        _Pragma("unroll")                                                  \
        for (int n = 0; n < 4; ++n)                                        \
            bfv[n] = *(const bf16x8*)(Bb_ + bBase + n * 1024);             \
        _Pragma("unroll")                                                  \
        for (int m = 0; m < 4; ++m)                                        \
            _Pragma("unroll")                                              \
            for (int n = 0; n < 4; ++n)                                    \
                acc[m][n] = __builtin_amdgcn_mfma_f32_16x16x32_bf16(       \
                    af[m], bfv[n], acc[m][n], 0, 0, 0);                    \
    }

    for (int k0 = 0; k0 < kLen; k0 += 64) {
        // even step: consume set X into buffer 0
        GSTAGE_WRITE(0, xa0, xa1, xb0, xb1);
        __syncthreads();
        if (k0 + 64 < kLen) {
            xa0 = *(const uint4*)(Ag + k0 + 64);
            xa1 = *(const uint4*)(Ag2 + k0 + 64);
            xb0 = *(const uint4*)(Bg + k0 + 64);
            xb1 = *(const uint4*)(Bg2 + k0 + 64);
        }
        GCOMPUTE(0);
        // odd step: consume set Y into buffer 1
        GSTAGE_WRITE(1, ya0, ya1, yb0, yb1);
        __syncthreads();
        if (k0 + 96 < kLen) {
            ya0 = *(const uint4*)(Ag + k0 + 96);
            ya1 = *(const uint4*)(Ag2 + k0 + 96);
            yb0 = *(const uint4*)(Bg + k0 + 96);
            yb1 = *(const uint4*)(Bg2 + k0 + 96);
        }
        GCOMPUTE(1);
    }
#undef GSTAGE_WRITE
#undef GCOMPUTE

    if (SPLITK > 1) {
        const size_t sb = (size_t)blockIdx.z * M;
#pragma unroll
        for (int m = 0; m < 4; ++m)
#pragma unroll
            for (int n = 0; n < 4; ++n) {
                int col = bn + wc * 64 + n * 16 + l15;
#pragma unroll
                for (int r = 0; r < 4; ++r) {
                    int row = bm + wr * 64 + m * 16 + l4 * 4 + r;
                    pout[(sb + row) * N + col] = acc[m][n][r];
                }
            }
    } else {
#pragma unroll
        for (int m = 0; m < 4; ++m)
#pragma unroll
            for (int n = 0; n < 4; ++n) {
                int col = bn + wc * 64 + n * 16 + l15;
                int row0 = bm + wr * 64 + m * 16 + l4 * 4;
                if (VSPLIT && col >= 2 * D) {
                    ushort4 pk;
                    pk.x = f2bf(acc[m][n][0]);
                    pk.y = f2bf(acc[m][n][1]);
                    pk.z = f2bf(acc[m][n][2]);
                    pk.w = f2bf(acc[m][n][3]);
                    *(ushort4*)(vTout + (size_t)(col - 2 * D) * L + row0) = pk;
                } else {
#pragma unroll
                    for (int r = 0; r < 4; ++r) {
                        int row = row0 + r;
                        float v = acc[m][n][r];
                        if (bias) v += bias[col];
                        if (ACT == 1) v = gelu_tanh(v);
                        if (resid) v += resid[(size_t)row * N + col];
                        if (OUTBF) outB[(size_t)row * N + col] = f2bf(v);
                        else       outF[(size_t)row * N + col] = v;
                    }
                }
            }
    }
}

// ------- MFMA flash attention, QBLK=64, KV-split over blockIdx.z, partials out ----
// Split s handles KV tiles [s*ceil(nt/NS), min(nt, ...)), emits f32 (o, m, l).
template <int NS>
__global__ __launch_bounds__(256) void attn_kernel(const ushort* __restrict__ qkv,
                                                   const ushort* __restrict__ vT,
                                                   const float* __restrict__ maskb,
                                                   float* __restrict__ po,
                                                   float* __restrict__ pm,
                                                   float* __restrict__ pl) {
    __shared__ __align__(16) char Kl[2][8192];
    __shared__ __align__(16) char Vl[2][8192];
    __shared__ float Ml[2][64];
    const int hh = blockIdx.y;
    const int sp = blockIdx.z;
    const int q0 = ((int)gridDim.x - 1 - (int)blockIdx.x) * 64;  // long blocks first
    const int tid = threadIdx.x;
    const int lane = tid & 63, w = tid >> 6;
    const int l15 = lane & 15, l4 = lane >> 4;
    const int qg = q0 + w * 16 + l15;
    const int qmin = q0 + w * 16;   // wave-uniform

    const int nt = q0 / 64 + 1;
    const int chunk = (nt + NS - 1) / NS;
    const int it0 = sp * chunk;
    int it1 = it0 + chunk;
    if (it1 > nt) it1 = nt;

    f32x4 o[4];
#pragma unroll
    for (int i = 0; i < 4; ++i) o[i] = (f32x4){0.f, 0.f, 0.f, 0.f};
    float mrun = -1e30f, lrun = 0.f;

    if (it0 < it1) {
        bf16x8 qf[2];
#pragma unroll
        for (int ks = 0; ks < 2; ++ks)
            qf[ks] = ldfrag(qkv + (size_t)qg * QKVN + hh * 64 + ks * 32 + l4 * 4);

        const int srow = tid >> 2, c = tid & 3;
        const int blo = (c & 1) * 32 + (c >> 1) * 8;
        const int swz = (srow & 7) << 4;
        const int rb = srow * 128;
        const int lo4 = blo & 15;
        const int s0 = rb + (((blo)      & 0x70) ^ swz) + lo4;
        const int s1 = rb + (((blo + 16) & 0x70) ^ swz) + lo4;
        const int s2 = rb + (((blo + 64) & 0x70) ^ swz) + lo4;
        const int s3 = rb + (((blo + 80) & 0x70) ^ swz) + lo4;
        const int fxor = (l15 & 7) << 4;

        const ushort* Ksrc = qkv + (size_t)srow * QKVN + D + hh * 64 + c * 8;
        const ushort* Vsrc = vT + (size_t)(hh * 64 + srow) * L + c * 8;

        uint4 ka, kb, va, vb;
        float mv = 0.f;
        {
            const size_t koff = (size_t)(it0 * 64) * QKVN;
            ka = *(const uint4*)(Ksrc + koff);
            kb = *(const uint4*)(Ksrc + koff + 32);
            va = *(const uint4*)(Vsrc + it0 * 64);
            vb = *(const uint4*)(Vsrc + it0 * 64 + 32);
            if (tid < 64) mv = maskb[it0 * 64 + tid];
        }

        for (int it = it0; it < it1; ++it) {
            const int kv0 = it * 64;
            const int b = it & 1;
            {
                char* Kb = Kl[b];
                char* Vb = Vl[b];
                uint2 t0, t1;
                t0.x = ka.x; t0.y = ka.y; t1.x = ka.z; t1.y = ka.w;
                *(uint2*)(Kb + s0) = t0;
                *(uint2*)(Kb + s1) = t1;
                t0.x = kb.x; t0.y = kb.y; t1.x = kb.z; t1.y = kb.w;
                *(uint2*)(Kb + s2) = t0;
                *(uint2*)(Kb + s3) = t1;
                t0.x = va.x; t0.y = va.y; t1.x = va.z; t1.y = va.w;
                *(uint2*)(Vb + s0) = t0;
                *(uint2*)(Vb + s1) = t1;
                t0.x = vb.x; t0.y = vb.y; t1.x = vb.z; t1.y = vb.w;
                *(uint2*)(Vb + s2) = t0;
                *(uint2*)(Vb + s3) = t1;
                if (tid < 64) Ml[b][tid] = mv;
            }
            __syncthreads();
            if (it + 1 < it1) {
                const size_t koff = (size_t)(kv0 + 64) * QKVN;
                ka = *(const uint4*)(Ksrc + koff);
                kb = *(const uint4*)(Ksrc + koff + 32);
                va = *(const uint4*)(Vsrc + kv0 + 64);
                vb = *(const uint4*)(Vsrc + kv0 + 96);
                if (tid < 64) mv = maskb[kv0 + 64 + tid];
            }

            const char* Kb = Kl[b];
            const char* Vb = Vl[b];

            f32x4 st[4];
#pragma unroll
            for (int m = 0; m < 4; ++m) st[m] = (f32x4){0.f, 0.f, 0.f, 0.f};
#pragma unroll
            for (int m = 0; m < 4; ++m)
#pragma unroll
                for (int ks = 0; ks < 2; ++ks) {
                    bf16x8 kf = *(const bf16x8*)(Kb + (m * 16 + l15) * 128 +
                                                 ((ks * 64 + l4 * 16) ^ fxor));
                    st[m] = __builtin_amdgcn_mfma_f32_16x16x32_bf16(kf, qf[ks], st[m], 0, 0, 0);
                }

            float p[4][4];
            float tmax = -1e30f;
            const bool full = (kv0 + 63 <= qmin);
            if (full) {
#pragma unroll
                for (int m = 0; m < 4; ++m)
#pragma unroll
                    for (int r = 0; r < 4; ++r) {
                        int kl = m * 16 + l4 * 4 + r;
                        float s = st[m][r] + Ml[b][kl];
                        p[m][r] = s;
                        tmax = fmaxf(tmax, s);
                    }
            } else {
#pragma unroll
                for (int m = 0; m < 4; ++m)
#pragma unroll
                    for (int r = 0; r < 4; ++r) {
                        int kl = m * 16 + l4 * 4 + r;
                        float s = st[m][r] + Ml[b][kl];
                        if (kv0 + kl > qg) s = -1e30f;
                        p[m][r] = s;
                        tmax = fmaxf(tmax, s);
                    }
            }
            tmax = fmaxf(tmax, __shfl_xor(tmax, 16));
            tmax = fmaxf(tmax, __shfl_xor(tmax, 32));
            const bool noresc = __all(tmax <= mrun);
            float mnew = noresc ? mrun : fmaxf(mrun, tmax);
            float scale = noresc ? 1.f : __expf(mrun - mnew);
            float ts = 0.f;
#pragma unroll
            for (int m = 0; m < 4; ++m)
#pragma unroll
                for (int r = 0; r < 4; ++r) {
                    float e = __expf(p[m][r] - mnew);
                    p[m][r] = e;
                    ts += e;
                }
            ts += __shfl_xor(ts, 16);
            ts += __shfl_xor(ts, 32);
            lrun = lrun * scale + ts;
            mrun = mnew;

            bf16x8 pf[2];
#pragma unroll
            for (int g = 0; g < 2; ++g) {
                union { bf16x8 v; uint32_t d[4]; } pu;
                pu.d[0] = cvt_pk_bf16(p[2 * g][0], p[2 * g][1]);
                pu.d[1] = cvt_pk_bf16(p[2 * g][2], p[2 * g][3]);
                pu.d[2] = cvt_pk_bf16(p[2 * g + 1][0], p[2 * g + 1][1]);
                pu.d[3] = cvt_pk_bf16(p[2 * g + 1][2], p[2 * g + 1][3]);
                pf[g] = pu.v;
            }
            if (!noresc) {
#pragma unroll
                for (int i = 0; i < 4; ++i) {
                    o[i][0] *= scale; o[i][1] *= scale; o[i][2] *= scale; o[i][3] *= scale;
                }
            }
#pragma unroll
            for (int dhb = 0; dhb < 4; ++dhb)
#pragma unroll
                for (int g = 0; g < 2; ++g) {
                    bf16x8 vf = *(const bf16x8*)(Vb + (dhb * 16 + l15) * 128 +
                                                 ((g * 64 + l4 * 16) ^ fxor));
                    o[dhb] = __builtin_amdgcn_mfma_f32_16x16x32_bf16(vf, pf[g], o[dhb], 0, 0, 0);
                }
        }
    }

    // write partials (o f32, m, l)
    const size_t pb = (size_t)(sp * H + hh) * L + qg;
    if (l4 == 0) { pm[pb] = mrun; pl[pb] = lrun; }
    float* op = po + pb * 64;
#pragma unroll
    for (int dhb = 0; dhb < 4; ++dhb)
        *(f32x4*)(op + dhb * 16 + l4 * 4) = o[dhb];
}

// ---------------- flash combine: merge NS partials -> bf16 ctx ----------------
template <int NS>
__global__ __launch_bounds__(256) void attn_combine(const float* __restrict__ po,
                                                    const float* __restrict__ pm,
                                                    const float* __restrict__ pl,
                                                    ushort* __restrict__ ctx) {
    const int hh = blockIdx.y;
    const int q = blockIdx.x * 64 + (threadIdx.x >> 2);
    const int d0 = (threadIdx.x & 3) * 16;
    size_t idx[NS];
    float mm = -1e30f;
#pragma unroll
    for (int s = 0; s < NS; ++s) {
        idx[s] = (size_t)(s * H + hh) * L + q;
        mm = fmaxf(mm, pm[idx[s]]);
    }
    float e[NS];
    float l = 0.f;
#pragma unroll
    for (int s = 0; s < NS; ++s) {
        e[s] = __expf(pm[idx[s]] - mm);
        l += pl[idx[s]] * e[s];
    }
    float rinv = 1.0f / l;
    ushort* cp = ctx + (size_t)q * D + hh * 64 + d0;
#pragma unroll
    for (int j = 0; j < 16; j += 4) {
        float acc[4] = {0.f, 0.f, 0.f, 0.f};
#pragma unroll
        for (int s = 0; s < NS; ++s) {
            const float* op = po + idx[s] * 64 + d0 + j;
            float4 v = *(const float4*)op;
            acc[0] += v.x * e[s];
            acc[1] += v.y * e[s];
            acc[2] += v.z * e[s];
            acc[3] += v.w * e[s];
        }
        ushort4 pk;
        pk.x = f2bf(acc[0] * rinv);
        pk.y = f2bf(acc[1] * rinv);
        pk.z = f2bf(acc[2] * rinv);
        pk.w = f2bf(acc[3] * rinv);
        *(ushort4*)(cp + j) = pk;
    }
}

extern "C" void kernel_launch(void* const* d_in, const int* in_sizes, int n_in,
                              void* d_out, int out_size, void* d_ws, size_t ws_size,
                              hipStream_t stream) {
    const int* ids = (const int*)d_in[0];
    const int* amask = (const int*)d_in[1];
    const float* wte = (const float*)d_in[2];
    const float* wpe = (const float*)d_in[3];
    const float* lnf_w = (const float*)d_in[4];
    const float* lnf_b = (const float*)d_in[5];
    const float* ln1_w = (const float*)d_in[6];
    const float* ln1_b = (const float*)d_in[7];
    const float* qw = (const float*)d_in[8];
    const float* kw = (const float*)d_in[9];
    const float* vw = (const float*)d_in[10];
    const float* ow = (const float*)d_in[11];
    const float* ob = (const float*)d_in[12];
    const float* ln2_w = (const float*)d_in[13];
    const float* ln2_b = (const float*)d_in[14];
    const float* fcw = (const float*)d_in[15];
    const float* fcb = (const float*)d_in[16];
    const float* pw = (const float*)d_in[17];
    const float* pb = (const float*)d_in[18];

    char* p = (char*)d_ws;
    auto take = [&](size_t bytes) -> char* {
        char* r = p;
        p += (bytes + 4095) & ~(size_t)4095;
        return r;
    };
    ushort* wqkvT = (ushort*)take((size_t)NL * QKVN * D * 2);
    ushort* woT   = (ushort*)take((size_t)NL * D * D * 2);
    ushort* fcwT  = (ushort*)take((size_t)NL * F * D * 2);
    ushort* pwT   = (ushort*)take((size_t)NL * D * F * 2);
    float*  h     = (float*)take((size_t)L * D * 4);
    ushort* xb    = (ushort*)take((size_t)L * D * 2);
    ushort* qkvb  = (ushort*)take((size_t)L * QKVN * 2);
    ushort* vTb   = (ushort*)take((size_t)D * L * 2);
    ushort* ctxb  = (ushort*)take((size_t)L * D * 2);
    ushort* f1b   = (ushort*)take((size_t)L * F * 2);
    float*  pk    = (float*)take((size_t)4 * L * D * 4);     // split-K partials
    float*  po    = (float*)take((size_t)2 * H * L * 64 * 4); // attn o partials
    float*  pm    = (float*)take((size_t)2 * H * L * 4);
    float*  pl    = (float*)take((size_t)2 * H * L * 4);
    float*  mb    = (float*)take(L * 4);
    int*    pos   = (int*)take(L * 4);

    pos_kernel<<<8, 256, 0, stream>>>(amask, pos);
    maskb_kernel<<<8, 256, 0, stream>>>(amask, mb);
    embed_kernel<<<L, 256, 0, stream>>>(ids, pos, wte, wpe, h);

    tcast_f32<<<dim3(12, 12, NL), 256, 0, stream>>>(qw, wqkvT, D, D,
                                                    (size_t)D * D, (size_t)QKVN * D);
    tcast_f32<<<dim3(12, 12, NL), 256, 0, stream>>>(kw, wqkvT + (size_t)D * D, D, D,
                                                    (size_t)D * D, (size_t)QKVN * D);
    tcast_f32<<<dim3(12, 12, NL), 256, 0, stream>>>(vw, wqkvT + (size_t)2 * D * D, D, D,
                                                    (size_t)D * D, (size_t)QKVN * D);
    tcast_f32<<<dim3(12, 12, NL), 256, 0, stream>>>(ow, woT, D, D,
                                                    (size_t)D * D, (size_t)D * D);
    tcast_f32<<<dim3(48, 12, NL), 256, 0, stream>>>(fcw, fcwT, D, F,
                                                    (size_t)D * F, (size_t)F * D);
    tcast_f32<<<dim3(12, 48, NL), 256, 0, stream>>>(pw, pwT, F, D,
                                                    (size_t)F * D, (size_t)D * F);

    ln_kernel<true><<<L, 256, 0, stream>>>(h, ln1_w, ln1_b, nullptr, xb);

    for (int l = 0; l < NL; ++l) {
        gemm_bf16<0, true, 1, true><<<dim3(QKVN / 128, L / 128), 256, 0, stream>>>(
            xb, wqkvT + (size_t)l * QKVN * D, nullptr, nullptr, nullptr, qkvb, nullptr,
            vTb, L, QKVN, D);
        attn_kernel<2><<<dim3(L / 64, H, 2), 256, 0, stream>>>(qkvb, vTb, mb,
                                                               po, pm, pl);
        attn_combine<2><<<dim3(L / 64, H), 256, 0, stream>>>(po, pm, pl, ctxb);
        gemm_bf16<0, true, 4, false><<<dim3(D / 128, L / 128, 4), 256, 0, stream>>>(
            ctxb, woT + (size_t)l * D * D, nullptr, nullptr, nullptr, nullptr, pk,
            nullptr, L, D, D);
        redln_kernel<4, true><<<L, 256, 0, stream>>>(
            pk, ob + l * D, h, ln2_w + l * D, ln2_b + l * D, xb, nullptr);
        gemm_bf16<1, true, 1, false><<<dim3(F / 128, L / 128), 256, 0, stream>>>(
            xb, fcwT + (size_t)l * F * D, fcb + l * F, nullptr, nullptr, f1b, nullptr,
            nullptr, L, F, D);
        gemm_bf16<0, true, 4, false><<<dim3(D / 128, L / 128, 4), 256, 0, stream>>>(
            f1b, pwT + (size_t)l * D * F, nullptr, nullptr, nullptr, nullptr, pk,
            nullptr, L, D, F);
        if (l < NL - 1) {
            redln_kernel<4, true><<<L, 256, 0, stream>>>(
                pk, pb + l * D, h, ln1_w + (l + 1) * D, ln1_b + (l + 1) * D, xb, nullptr);
        } else {
            redln_kernel<4, false><<<L, 256, 0, stream>>>(
                pk, pb + l * D, h, lnf_w, lnf_b, nullptr, (float*)d_out);
        }
    }
}

// Round 10
// 1777.099 us; speedup vs baseline: 1.1730x; 1.0174x over previous
//
#include <hip/hip_runtime.h>
#include <hip/hip_bf16.h>
#include <math.h>
#include <stdint.h>

#define L 2048
#define D 768
#define H 12
#define DH 64
#define F 3072
#define NL 12
#define QKVN 2304

typedef __attribute__((ext_vector_type(8))) short bf16x8;
typedef __attribute__((ext_vector_type(4))) float f32x4;

__device__ __forceinline__ ushort f2bf(float x) {
    union { float f; uint32_t u; } c; c.f = x;
    uint32_t r = c.u + 0x7FFFu + ((c.u >> 16) & 1u);
    return (ushort)(r >> 16);
}

// pack two f32 -> one dword of two bf16 (RNE)
__device__ __forceinline__ uint32_t cvt_pk_bf16(float lo, float hi) {
    uint32_t r;
    asm("v_cvt_pk_bf16_f32 %0, %1, %2" : "=v"(r) : "v"(lo), "v"(hi));
    return r;
}

// raw 2^x (v_exp_f32 is natively base-2)
__device__ __forceinline__ float ex2(float x) {
    float r;
    asm("v_exp_f32 %0, %1" : "=v"(r) : "v"(x));
    return r;
}

#define LOG2E 1.4426950408889634f

__device__ __forceinline__ bf16x8 ldfrag(const ushort* p) {
    ushort4 lo = *(const ushort4*)(p);
    ushort4 hi = *(const ushort4*)(p + 16);
    bf16x8 f;
    f[0] = (short)lo.x; f[1] = (short)lo.y; f[2] = (short)lo.z; f[3] = (short)lo.w;
    f[4] = (short)hi.x; f[5] = (short)hi.y; f[6] = (short)hi.z; f[7] = (short)hi.w;
    return f;
}

__device__ __forceinline__ float gelu_tanh(float x) {
    float c = 0.7978845608028654f;
    float inner = c * (x + 0.044715f * x * x * x);
    return 0.5f * x * (1.0f + tanhf(inner));
}

// ---------------- position cumsum ----------------
__global__ void pos_kernel(const int* __restrict__ mask, int* __restrict__ pos) {
    __shared__ int sm[L];
    for (int i = threadIdx.x; i < L; i += blockDim.x) sm[i] = mask[i];
    __syncthreads();
    int t = blockIdx.x * blockDim.x + threadIdx.x;
    if (t < L) {
        int s = 0;
        for (int j = 0; j <= t; ++j) s += sm[j];
        int p = s - 1;
        if (sm[t] == 0) p = 1;
        pos[t] = p;
    }
}

// mask bias pre-scaled for the log2-domain softmax
__global__ void maskb_kernel(const int* __restrict__ mask, float* __restrict__ mb) {
    int i = blockIdx.x * blockDim.x + threadIdx.x;
    if (i < L) mb[i] = mask[i] ? 0.f : -2.0e9f;
}

// ---------------- embedding ----------------
__global__ __launch_bounds__(256) void embed_kernel(const int* __restrict__ ids,
                                                    const int* __restrict__ pos,
                                                    const float* __restrict__ wte,
                                                    const float* __restrict__ wpe,
                                                    float* __restrict__ h) {
    int t = blockIdx.x;
    int id = ids[t];
    int p = pos[t];
    const float* we = wte + (size_t)id * D;
    const float* wp = wpe + (size_t)p * D;
    float* hr = h + (size_t)t * D;
#pragma unroll
    for (int i = 0; i < 3; ++i) {
        int d = threadIdx.x + i * 256;
        hr[d] = we[d] + wp[d];
    }
}

// ---------------- layernorm (f32 in, bf16 out) ----------------
template <bool OUTBF>
__global__ __launch_bounds__(256) void ln_kernel(const float* __restrict__ in,
                                                 const float* __restrict__ w,
                                                 const float* __restrict__ b,
                                                 float* __restrict__ outF,
                                                 ushort* __restrict__ outB) {
    __shared__ float red[2][4];
    int row = blockIdx.x;
    const float* x = in + (size_t)row * D;
    int t = threadIdx.x;
    float v0 = x[t], v1 = x[t + 256], v2 = x[t + 512];
    float s = v0 + v1 + v2;
    float ss = v0 * v0 + v1 * v1 + v2 * v2;
#pragma unroll
    for (int o = 32; o; o >>= 1) {
        s += __shfl_xor(s, o);
        ss += __shfl_xor(ss, o);
    }
    int wave = t >> 6;
    if ((t & 63) == 0) { red[0][wave] = s; red[1][wave] = ss; }
    __syncthreads();
    s = red[0][0] + red[0][1] + red[0][2] + red[0][3];
    ss = red[1][0] + red[1][1] + red[1][2] + red[1][3];
    float mean = s * (1.f / D);
    float var = ss * (1.f / D) - mean * mean;
    float rstd = rsqrtf(var + 1e-5f);
#pragma unroll
    for (int i = 0; i < 3; ++i) {
        int d = t + i * 256;
        float vv = (i == 0) ? v0 : (i == 1) ? v1 : v2;
        float y = (vv - mean) * rstd * w[d] + b[d];
        if (OUTBF) outB[(size_t)row * D + d] = f2bf(y);
        else       outF[(size_t)row * D + d] = y;
    }
}

// ---- fused split-K reduce + bias + residual(h) + LayerNorm -> bf16 (or f32) ----
template <int S, bool OUTBF>
__global__ __launch_bounds__(256) void redln_kernel(const float* __restrict__ part,
                                                    const float* __restrict__ bias,
                                                    float* __restrict__ h,
                                                    const float* __restrict__ lnw,
                                                    const float* __restrict__ lnb,
                                                    ushort* __restrict__ outB,
                                                    float* __restrict__ outF) {
    __shared__ float red[2][4];
    int row = blockIdx.x;
    int t = threadIdx.x;
    float v[3];
    float s = 0.f, ss = 0.f;
#pragma unroll
    for (int i = 0; i < 3; ++i) {
        int d = t + i * 256;
        float x = h[(size_t)row * D + d] + bias[d];
#pragma unroll
        for (int sp = 0; sp < S; ++sp)
            x += part[((size_t)sp * L + row) * D + d];
        v[i] = x;
        h[(size_t)row * D + d] = x;
        s += x;
        ss += x * x;
    }
#pragma unroll
    for (int o = 32; o; o >>= 1) {
        s += __shfl_xor(s, o);
        ss += __shfl_xor(ss, o);
    }
    int wave = t >> 6;
    if ((t & 63) == 0) { red[0][wave] = s; red[1][wave] = ss; }
    __syncthreads();
    s = red[0][0] + red[0][1] + red[0][2] + red[0][3];
    ss = red[1][0] + red[1][1] + red[1][2] + red[1][3];
    float mean = s * (1.f / D);
    float var = ss * (1.f / D) - mean * mean;
    float rstd = rsqrtf(var + 1e-5f);
#pragma unroll
    for (int i = 0; i < 3; ++i) {
        int d = t + i * 256;
        float y = (v[i] - mean) * rstd * lnw[d] + lnb[d];
        if (OUTBF) outB[(size_t)row * D + d] = f2bf(y);
        else       outF[(size_t)row * D + d] = y;
    }
}

// ---------------- transpose-cast f32 [K][N] -> bf16 [N][K], z = layer ----------------
__global__ __launch_bounds__(256) void tcast_f32(const float* __restrict__ in,
                                                 ushort* __restrict__ out,
                                                 int K, int N,
                                                 size_t inStride, size_t outStride) {
    in += blockIdx.z * inStride;
    out += blockIdx.z * outStride;
    __shared__ float tile[64][65];
    int k0 = blockIdx.y * 64, n0 = blockIdx.x * 64;
    int t = threadIdx.x;
    int cl = t & 63, rg = t >> 6;
#pragma unroll
    for (int i = 0; i < 16; ++i) {
        int r = rg + 4 * i;
        tile[r][cl] = in[(size_t)(k0 + r) * N + n0 + cl];
    }
    __syncthreads();
#pragma unroll
    for (int i = 0; i < 16; ++i) {
        int r = rg + 4 * i;
        out[(size_t)(n0 + r) * K + k0 + cl] = f2bf(tile[cl][r]);
    }
}

// ---------------- bf16 MFMA GEMM, 128x128 tile, BK=64, dbuf LDS, 1 barrier/step ----
// LDS row = 128 B (all 64 k-elems), k-permuted 16B chunks + (row&7)<<4 XOR so a
// fragment = one clean ds_read_b128 (same layout as the attention kernel).
// VSPLIT: for the QKV GEMM, cols >= 2*D (V projection) are written transposed.
// SPLITK>1: blockIdx.z splits K; f32 partials to pout.
template <int ACT, bool OUTBF, int SPLITK, bool VSPLIT>
__global__ __launch_bounds__(256) void gemm_bf16(const ushort* __restrict__ A,
                                                 const ushort* __restrict__ Bt,
                                                 const float* __restrict__ bias,
                                                 const float* __restrict__ resid,
                                                 float* __restrict__ outF,
                                                 ushort* __restrict__ outB,
                                                 float* __restrict__ pout,
                                                 ushort* __restrict__ vTout,
                                                 int M, int N, int K) {
    __shared__ __align__(16) char lds[65536];   // 2 buf x (A 16K + B 16K)
    const int tid = threadIdx.x;
    const int lane = tid & 63, w = tid >> 6;
    const int wr = w >> 1, wc = w & 1;
    const int bm = blockIdx.y * 128, bn = blockIdx.x * 128;
    const int l15 = lane & 15, l4 = lane >> 4;
    const int kLen = K / SPLITK;
    const int kStart = (SPLITK > 1) ? blockIdx.z * kLen : 0;

    // staging geometry: 256 threads over 128 rows, thread = (row, 64B-half)
    const int srow = tid >> 1, hf = tid & 1;
    const int swz = (srow & 7) << 4;
    const int rb = srow * 128;
    int offlo[4], offhi[4];
#pragma unroll
    for (int cc = 0; cc < 4; ++cc) {
        int blo = (cc & 1) * 32 + ((cc >> 1) & 1) * 8 + hf * 64;
        offlo[cc] = rb + ((blo & 0x70) ^ swz) + (blo & 15);
        int bhi = blo + 16;
        offhi[cc] = rb + ((bhi & 0x70) ^ swz) + (bhi & 15);
    }
    const int fxor = (l15 & 7) << 4;

    f32x4 acc[4][4];
#pragma unroll
    for (int m = 0; m < 4; ++m)
#pragma unroll
        for (int n = 0; n < 4; ++n)
            acc[m][n] = (f32x4){0.f, 0.f, 0.f, 0.f};

    const ushort* Ag = A + (size_t)(bm + srow) * K + kStart + hf * 32;
    const ushort* Bg = Bt + (size_t)(bn + srow) * K + kStart + hf * 32;

    uint4 ax[4], bx[4];
#pragma unroll
    for (int cc = 0; cc < 4; ++cc) {
        ax[cc] = *(const uint4*)(Ag + cc * 8);
        bx[cc] = *(const uint4*)(Bg + cc * 8);
    }

    for (int k0 = 0; k0 < kLen; k0 += 64) {
        char* Ab = lds + ((k0 >> 6) & 1) * 32768;
        char* Bb = Ab + 16384;
        {
            uint2 t0, t1;
#pragma unroll
            for (int cc = 0; cc < 4; ++cc) {
                t0.x = ax[cc].x; t0.y = ax[cc].y; t1.x = ax[cc].z; t1.y = ax[cc].w;
                *(uint2*)(Ab + offlo[cc]) = t0;
                *(uint2*)(Ab + offhi[cc]) = t1;
                t0.x = bx[cc].x; t0.y = bx[cc].y; t1.x = bx[cc].z; t1.y = bx[cc].w;
                *(uint2*)(Bb + offlo[cc]) = t0;
                *(uint2*)(Bb + offhi[cc]) = t1;
            }
        }
        __syncthreads();
        if (k0 + 64 < kLen) {
#pragma unroll
            for (int cc = 0; cc < 4; ++cc) {
                ax[cc] = *(const uint4*)(Ag + k0 + 64 + cc * 8);
                bx[cc] = *(const uint4*)(Bg + k0 + 64 + cc * 8);
            }
        }
        bf16x8 af[4][2], bfv[4][2];
#pragma unroll
        for (int m = 0; m < 4; ++m)
#pragma unroll
            for (int ks = 0; ks < 2; ++ks)
                af[m][ks] = *(const bf16x8*)(Ab + (wr * 64 + m * 16 + l15) * 128 +
                                             ((ks * 64 + l4 * 16) ^ fxor));
#pragma unroll
        for (int n = 0; n < 4; ++n)
#pragma unroll
            for (int ks = 0; ks < 2; ++ks)
                bfv[n][ks] = *(const bf16x8*)(Bb + (wc * 64 + n * 16 + l15) * 128 +
                                              ((ks * 64 + l4 * 16) ^ fxor));
#pragma unroll
        for (int m = 0; m < 4; ++m)
#pragma unroll
            for (int n = 0; n < 4; ++n) {
                acc[m][n] = __builtin_amdgcn_mfma_f32_16x16x32_bf16(
                    af[m][0], bfv[n][0], acc[m][n], 0, 0, 0);
                acc[m][n] = __builtin_amdgcn_mfma_f32_16x16x32_bf16(
                    af[m][1], bfv[n][1], acc[m][n], 0, 0, 0);
            }
        // no trailing barrier: the next iteration writes the OTHER buffer; its
        // barrier (collective) orders this buffer's reads vs its next overwrite.
    }

    if (SPLITK > 1) {
        const size_t sb = (size_t)blockIdx.z * M;
#pragma unroll
        for (int m = 0; m < 4; ++m)
#pragma unroll
            for (int n = 0; n < 4; ++n) {
                int col = bn + wc * 64 + n * 16 + l15;
#pragma unroll
                for (int r = 0; r < 4; ++r) {
                    int row = bm + wr * 64 + m * 16 + l4 * 4 + r;
                    pout[(sb + row) * N + col] = acc[m][n][r];
                }
            }
    } else {
#pragma unroll
        for (int m = 0; m < 4; ++m)
#pragma unroll
            for (int n = 0; n < 4; ++n) {
                int col = bn + wc * 64 + n * 16 + l15;
                int row0 = bm + wr * 64 + m * 16 + l4 * 4;
                if (VSPLIT && col >= 2 * D) {
                    ushort4 pk;
                    pk.x = f2bf(acc[m][n][0]);
                    pk.y = f2bf(acc[m][n][1]);
                    pk.z = f2bf(acc[m][n][2]);
                    pk.w = f2bf(acc[m][n][3]);
                    *(ushort4*)(vTout + (size_t)(col - 2 * D) * L + row0) = pk;
                } else {
#pragma unroll
                    for (int r = 0; r < 4; ++r) {
                        int row = row0 + r;
                        float v = acc[m][n][r];
                        if (bias) v += bias[col];
                        if (ACT == 1) v = gelu_tanh(v);
                        if (resid) v += resid[(size_t)row * N + col];
                        if (OUTBF) outB[(size_t)row * N + col] = f2bf(v);
                        else       outF[(size_t)row * N + col] = v;
                    }
                }
            }
    }
}

// ------- MFMA flash attention, QBLK=64, KV-split over blockIdx.z, partials out ----
// Softmax in log2 domain: scores scaled by log2e via fma, 2^x via v_exp_f32.
template <int NS>
__global__ __launch_bounds__(256) void attn_kernel(const ushort* __restrict__ qkv,
                                                   const ushort* __restrict__ vT,
                                                   const float* __restrict__ maskb,
                                                   float* __restrict__ po,
                                                   float* __restrict__ pm,
                                                   float* __restrict__ pl) {
    __shared__ __align__(16) char Kl[2][8192];
    __shared__ __align__(16) char Vl[2][8192];
    __shared__ float Ml[2][64];
    const int hh = blockIdx.y;
    const int sp = blockIdx.z;
    const int q0 = ((int)gridDim.x - 1 - (int)blockIdx.x) * 64;  // long blocks first
    const int tid = threadIdx.x;
    const int lane = tid & 63, w = tid >> 6;
    const int l15 = lane & 15, l4 = lane >> 4;
    const int qg = q0 + w * 16 + l15;
    const int qmin = q0 + w * 16;   // wave-uniform

    const int nt = q0 / 64 + 1;
    const int chunk = (nt + NS - 1) / NS;
    const int it0 = sp * chunk;
    int it1 = it0 + chunk;
    if (it1 > nt) it1 = nt;

    f32x4 o[4];
#pragma unroll
    for (int i = 0; i < 4; ++i) o[i] = (f32x4){0.f, 0.f, 0.f, 0.f};
    float mrun = -1e30f, lrun = 0.f;

    if (it0 < it1) {
        bf16x8 qf[2];
#pragma unroll
        for (int ks = 0; ks < 2; ++ks)
            qf[ks] = ldfrag(qkv + (size_t)qg * QKVN + hh * 64 + ks * 32 + l4 * 4);

        const int srow = tid >> 2, c = tid & 3;
        const int blo = (c & 1) * 32 + (c >> 1) * 8;
        const int swz = (srow & 7) << 4;
        const int rb = srow * 128;
        const int lo4 = blo & 15;
        const int s0 = rb + (((blo)      & 0x70) ^ swz) + lo4;
        const int s1 = rb + (((blo + 16) & 0x70) ^ swz) + lo4;
        const int s2 = rb + (((blo + 64) & 0x70) ^ swz) + lo4;
        const int s3 = rb + (((blo + 80) & 0x70) ^ swz) + lo4;
        const int fxor = (l15 & 7) << 4;

        const ushort* Ksrc = qkv + (size_t)srow * QKVN + D + hh * 64 + c * 8;
        const ushort* Vsrc = vT + (size_t)(hh * 64 + srow) * L + c * 8;

        uint4 ka, kb, va, vb;
        float mv = 0.f;
        {
            const size_t koff = (size_t)(it0 * 64) * QKVN;
            ka = *(const uint4*)(Ksrc + koff);
            kb = *(const uint4*)(Ksrc + koff + 32);
            va = *(const uint4*)(Vsrc + it0 * 64);
            vb = *(const uint4*)(Vsrc + it0 * 64 + 32);
            if (tid < 64) mv = maskb[it0 * 64 + tid];
        }

        for (int it = it0; it < it1; ++it) {
            const int kv0 = it * 64;
            const int b = it & 1;
            {
                char* Kb = Kl[b];
                char* Vb = Vl[b];
                uint2 t0, t1;
                t0.x = ka.x; t0.y = ka.y; t1.x = ka.z; t1.y = ka.w;
                *(uint2*)(Kb + s0) = t0;
                *(uint2*)(Kb + s1) = t1;
                t0.x = kb.x; t0.y = kb.y; t1.x = kb.z; t1.y = kb.w;
                *(uint2*)(Kb + s2) = t0;
                *(uint2*)(Kb + s3) = t1;
                t0.x = va.x; t0.y = va.y; t1.x = va.z; t1.y = va.w;
                *(uint2*)(Vb + s0) = t0;
                *(uint2*)(Vb + s1) = t1;
                t0.x = vb.x; t0.y = vb.y; t1.x = vb.z; t1.y = vb.w;
                *(uint2*)(Vb + s2) = t0;
                *(uint2*)(Vb + s3) = t1;
                if (tid < 64) Ml[b][tid] = mv;
            }
            __syncthreads();
            if (it + 1 < it1) {
                const size_t koff = (size_t)(kv0 + 64) * QKVN;
                ka = *(const uint4*)(Ksrc + koff);
                kb = *(const uint4*)(Ksrc + koff + 32);
                va = *(const uint4*)(Vsrc + kv0 + 64);
                vb = *(const uint4*)(Vsrc + kv0 + 96);
                if (tid < 64) mv = maskb[kv0 + 64 + tid];
            }

            const char* Kb = Kl[b];
            const char* Vb = Vl[b];

            f32x4 st[4];
#pragma unroll
            for (int m = 0; m < 4; ++m) st[m] = (f32x4){0.f, 0.f, 0.f, 0.f};
#pragma unroll
            for (int m = 0; m < 4; ++m)
#pragma unroll
                for (int ks = 0; ks < 2; ++ks) {
                    bf16x8 kf = *(const bf16x8*)(Kb + (m * 16 + l15) * 128 +
                                                 ((ks * 64 + l4 * 16) ^ fxor));
                    st[m] = __builtin_amdgcn_mfma_f32_16x16x32_bf16(kf, qf[ks], st[m], 0, 0, 0);
                }

            float p[4][4];
            float tmax = -1e30f;
            const bool full = (kv0 + 63 <= qmin);
            if (full) {
#pragma unroll
                for (int m = 0; m < 4; ++m)
#pragma unroll
                    for (int r = 0; r < 4; ++r) {
                        int kl = m * 16 + l4 * 4 + r;
                        float s = fmaf(st[m][r], LOG2E, Ml[b][kl]);
                        p[m][r] = s;
                        tmax = fmaxf(tmax, s);
                    }
            } else {
#pragma unroll
                for (int m = 0; m < 4; ++m)
#pragma unroll
                    for (int r = 0; r < 4; ++r) {
                        int kl = m * 16 + l4 * 4 + r;
                        float s = fmaf(st[m][r], LOG2E, Ml[b][kl]);
                        if (kv0 + kl > qg) s = -1e30f;
                        p[m][r] = s;
                        tmax = fmaxf(tmax, s);
                    }
            }
            tmax = fmaxf(tmax, __shfl_xor(tmax, 16));
            tmax = fmaxf(tmax, __shfl_xor(tmax, 32));
            const bool noresc = __all(tmax <= mrun);
            float mnew = noresc ? mrun : fmaxf(mrun, tmax);
            float scale = noresc ? 1.f : ex2(mrun - mnew);
            float ts = 0.f;
#pragma unroll
            for (int m = 0; m < 4; ++m)
#pragma unroll
                for (int r = 0; r < 4; ++r) {
                    float e = ex2(p[m][r] - mnew);
                    p[m][r] = e;
                    ts += e;
                }
            ts += __shfl_xor(ts, 16);
            ts += __shfl_xor(ts, 32);
            lrun = lrun * scale + ts;
            mrun = mnew;

            bf16x8 pf[2];
#pragma unroll
            for (int g = 0; g < 2; ++g) {
                union { bf16x8 v; uint32_t d[4]; } pu;
                pu.d[0] = cvt_pk_bf16(p[2 * g][0], p[2 * g][1]);
                pu.d[1] = cvt_pk_bf16(p[2 * g][2], p[2 * g][3]);
                pu.d[2] = cvt_pk_bf16(p[2 * g + 1][0], p[2 * g + 1][1]);
                pu.d[3] = cvt_pk_bf16(p[2 * g + 1][2], p[2 * g + 1][3]);
                pf[g] = pu.v;
            }
            if (!noresc) {
#pragma unroll
                for (int i = 0; i < 4; ++i) {
                    o[i][0] *= scale; o[i][1] *= scale; o[i][2] *= scale; o[i][3] *= scale;
                }
            }
#pragma unroll
            for (int dhb = 0; dhb < 4; ++dhb)
#pragma unroll
                for (int g = 0; g < 2; ++g) {
                    bf16x8 vf = *(const bf16x8*)(Vb + (dhb * 16 + l15) * 128 +
                                                 ((g * 64 + l4 * 16) ^ fxor));
                    o[dhb] = __builtin_amdgcn_mfma_f32_16x16x32_bf16(vf, pf[g], o[dhb], 0, 0, 0);
                }
        }
    }

    // write partials (o f32, m in log2 units, l)
    const size_t pb = (size_t)(sp * H + hh) * L + qg;
    if (l4 == 0) { pm[pb] = mrun; pl[pb] = lrun; }
    float* op = po + pb * 64;
#pragma unroll
    for (int dhb = 0; dhb < 4; ++dhb)
        *(f32x4*)(op + dhb * 16 + l4 * 4) = o[dhb];
}

// ---------------- flash combine (log2 domain): merge NS partials -> bf16 ctx ----
template <int NS>
__global__ __launch_bounds__(256) void attn_combine(const float* __restrict__ po,
                                                    const float* __restrict__ pm,
                                                    const float* __restrict__ pl,
                                                    ushort* __restrict__ ctx) {
    const int hh = blockIdx.y;
    const int q = blockIdx.x * 64 + (threadIdx.x >> 2);
    const int d0 = (threadIdx.x & 3) * 16;
    size_t idx[NS];
    float mm = -1e30f;
#pragma unroll
    for (int s = 0; s < NS; ++s) {
        idx[s] = (size_t)(s * H + hh) * L + q;
        mm = fmaxf(mm, pm[idx[s]]);
    }
    float e[NS];
    float l = 0.f;
#pragma unroll
    for (int s = 0; s < NS; ++s) {
        e[s] = ex2(pm[idx[s]] - mm);
        l += pl[idx[s]] * e[s];
    }
    float rinv = 1.0f / l;
    ushort* cp = ctx + (size_t)q * D + hh * 64 + d0;
#pragma unroll
    for (int j = 0; j < 16; j += 4) {
        float acc[4] = {0.f, 0.f, 0.f, 0.f};
#pragma unroll
        for (int s = 0; s < NS; ++s) {
            const float* op = po + idx[s] * 64 + d0 + j;
            float4 v = *(const float4*)op;
            acc[0] += v.x * e[s];
            acc[1] += v.y * e[s];
            acc[2] += v.z * e[s];
            acc[3] += v.w * e[s];
        }
        ushort4 pk;
        pk.x = f2bf(acc[0] * rinv);
        pk.y = f2bf(acc[1] * rinv);
        pk.z = f2bf(acc[2] * rinv);
        pk.w = f2bf(acc[3] * rinv);
        *(ushort4*)(cp + j) = pk;
    }
}

extern "C" void kernel_launch(void* const* d_in, const int* in_sizes, int n_in,
                              void* d_out, int out_size, void* d_ws, size_t ws_size,
                              hipStream_t stream) {
    const int* ids = (const int*)d_in[0];
    const int* amask = (const int*)d_in[1];
    const float* wte = (const float*)d_in[2];
    const float* wpe = (const float*)d_in[3];
    const float* lnf_w = (const float*)d_in[4];
    const float* lnf_b = (const float*)d_in[5];
    const float* ln1_w = (const float*)d_in[6];
    const float* ln1_b = (const float*)d_in[7];
    const float* qw = (const float*)d_in[8];
    const float* kw = (const float*)d_in[9];
    const float* vw = (const float*)d_in[10];
    const float* ow = (const float*)d_in[11];
    const float* ob = (const float*)d_in[12];
    const float* ln2_w = (const float*)d_in[13];
    const float* ln2_b = (const float*)d_in[14];
    const float* fcw = (const float*)d_in[15];
    const float* fcb = (const float*)d_in[16];
    const float* pw = (const float*)d_in[17];
    const float* pb = (const float*)d_in[18];

    char* p = (char*)d_ws;
    auto take = [&](size_t bytes) -> char* {
        char* r = p;
        p += (bytes + 4095) & ~(size_t)4095;
        return r;
    };
    ushort* wqkvT = (ushort*)take((size_t)NL * QKVN * D * 2);
    ushort* woT   = (ushort*)take((size_t)NL * D * D * 2);
    ushort* fcwT  = (ushort*)take((size_t)NL * F * D * 2);
    ushort* pwT   = (ushort*)take((size_t)NL * D * F * 2);
    float*  h     = (float*)take((size_t)L * D * 4);
    ushort* xb    = (ushort*)take((size_t)L * D * 2);
    ushort* qkvb  = (ushort*)take((size_t)L * QKVN * 2);
    ushort* vTb   = (ushort*)take((size_t)D * L * 2);
    ushort* ctxb  = (ushort*)take((size_t)L * D * 2);
    ushort* f1b   = (ushort*)take((size_t)L * F * 2);
    float*  pk    = (float*)take((size_t)4 * L * D * 4);     // split-K partials
    float*  po    = (float*)take((size_t)2 * H * L * 64 * 4); // attn o partials
    float*  pm    = (float*)take((size_t)2 * H * L * 4);
    float*  pl    = (float*)take((size_t)2 * H * L * 4);
    float*  mb    = (float*)take(L * 4);
    int*    pos   = (int*)take(L * 4);

    pos_kernel<<<8, 256, 0, stream>>>(amask, pos);
    maskb_kernel<<<8, 256, 0, stream>>>(amask, mb);
    embed_kernel<<<L, 256, 0, stream>>>(ids, pos, wte, wpe, h);

    tcast_f32<<<dim3(12, 12, NL), 256, 0, stream>>>(qw, wqkvT, D, D,
                                                    (size_t)D * D, (size_t)QKVN * D);
    tcast_f32<<<dim3(12, 12, NL), 256, 0, stream>>>(kw, wqkvT + (size_t)D * D, D, D,
                                                    (size_t)D * D, (size_t)QKVN * D);
    tcast_f32<<<dim3(12, 12, NL), 256, 0, stream>>>(vw, wqkvT + (size_t)2 * D * D, D, D,
                                                    (size_t)D * D, (size_t)QKVN * D);
    tcast_f32<<<dim3(12, 12, NL), 256, 0, stream>>>(ow, woT, D, D,
                                                    (size_t)D * D, (size_t)D * D);
    tcast_f32<<<dim3(48, 12, NL), 256, 0, stream>>>(fcw, fcwT, D, F,
                                                    (size_t)D * F, (size_t)F * D);
    tcast_f32<<<dim3(12, 48, NL), 256, 0, stream>>>(pw, pwT, F, D,
                                                    (size_t)F * D, (size_t)D * F);

    ln_kernel<true><<<L, 256, 0, stream>>>(h, ln1_w, ln1_b, nullptr, xb);

    for (int l = 0; l < NL; ++l) {
        gemm_bf16<0, true, 1, true><<<dim3(QKVN / 128, L / 128), 256, 0, stream>>>(
            xb, wqkvT + (size_t)l * QKVN * D, nullptr, nullptr, nullptr, qkvb, nullptr,
            vTb, L, QKVN, D);
        attn_kernel<2><<<dim3(L / 64, H, 2), 256, 0, stream>>>(qkvb, vTb, mb,
                                                               po, pm, pl);
        attn_combine<2><<<dim3(L / 64, H), 256, 0, stream>>>(po, pm, pl, ctxb);
        gemm_bf16<0, true, 4, false><<<dim3(D / 128, L / 128, 4), 256, 0, stream>>>(
            ctxb, woT + (size_t)l * D * D, nullptr, nullptr, nullptr, nullptr, pk,
            nullptr, L, D, D);
        redln_kernel<4, true><<<L, 256, 0, stream>>>(
            pk, ob + l * D, h, ln2_w + l * D, ln2_b + l * D, xb, nullptr);
        gemm_bf16<1, true, 1, false><<<dim3(F / 128, L / 128), 256, 0, stream>>>(
            xb, fcwT + (size_t)l * F * D, fcb + l * F, nullptr, nullptr, f1b, nullptr,
            nullptr, L, F, D);
        gemm_bf16<0, true, 4, false><<<dim3(D / 128, L / 128, 4), 256, 0, stream>>>(
            f1b, pwT + (size_t)l * D * F, nullptr, nullptr, nullptr, nullptr, pk,
            nullptr, L, D, F);
        if (l < NL - 1) {
            redln_kernel<4, true><<<L, 256, 0, stream>>>(
                pk, pb + l * D, h, ln1_w + (l + 1) * D, ln1_b + (l + 1) * D, xb, nullptr);
        } else {
            redln_kernel<4, false><<<L, 256, 0, stream>>>(
                pk, pb + l * D, h, lnf_w, lnf_b, nullptr, (float*)d_out);
        }
    }
}

// Round 11
// 1772.543 us; speedup vs baseline: 1.1760x; 1.0026x over previous
//
#include <hip/hip_runtime.h>
#include <hip/hip_bf16.h>
#include <math.h>
#include <stdint.h>

#define L 2048
#define D 768
#define H 12
#define DH 64
#define F 3072
#define NL 12
#define QKVN 2304

typedef __attribute__((ext_vector_type(8))) short bf16x8;
typedef __attribute__((ext_vector_type(4))) float f32x4;

__device__ __forceinline__ ushort f2bf(float x) {
    union { float f; uint32_t u; } c; c.f = x;
    uint32_t r = c.u + 0x7FFFu + ((c.u >> 16) & 1u);
    return (ushort)(r >> 16);
}

// pack two f32 -> one dword of two bf16 (RNE)
__device__ __forceinline__ uint32_t cvt_pk_bf16(float lo, float hi) {
    uint32_t r;
    asm("v_cvt_pk_bf16_f32 %0, %1, %2" : "=v"(r) : "v"(lo), "v"(hi));
    return r;
}

// raw 2^x (v_exp_f32 is natively base-2)
__device__ __forceinline__ float ex2(float x) {
    float r;
    asm("v_exp_f32 %0, %1" : "=v"(r) : "v"(x));
    return r;
}

#define LOG2E 1.4426950408889634f

__device__ __forceinline__ bf16x8 ldfrag(const ushort* p) {
    ushort4 lo = *(const ushort4*)(p);
    ushort4 hi = *(const ushort4*)(p + 16);
    bf16x8 f;
    f[0] = (short)lo.x; f[1] = (short)lo.y; f[2] = (short)lo.z; f[3] = (short)lo.w;
    f[4] = (short)hi.x; f[5] = (short)hi.y; f[6] = (short)hi.z; f[7] = (short)hi.w;
    return f;
}

// gelu tanh-approx with fast exp2-based tanh (clamped; |err| ~1e-7)
__device__ __forceinline__ float gelu_tanh(float x) {
    float c = 0.7978845608028654f;
    float u = c * (x + 0.044715f * x * x * x);
    u = fminf(fmaxf(u, -10.f), 10.f);
    float t = ex2(u * (2.0f * LOG2E));      // e^(2u)
    float th = (t - 1.0f) / (t + 1.0f);     // tanh(u)
    return 0.5f * x * (1.0f + th);
}

// ---------------- position cumsum ----------------
__global__ void pos_kernel(const int* __restrict__ mask, int* __restrict__ pos) {
    __shared__ int sm[L];
    for (int i = threadIdx.x; i < L; i += blockDim.x) sm[i] = mask[i];
    __syncthreads();
    int t = blockIdx.x * blockDim.x + threadIdx.x;
    if (t < L) {
        int s = 0;
        for (int j = 0; j <= t; ++j) s += sm[j];
        int p = s - 1;
        if (sm[t] == 0) p = 1;
        pos[t] = p;
    }
}

// mask bias pre-scaled for the log2-domain softmax
__global__ void maskb_kernel(const int* __restrict__ mask, float* __restrict__ mb) {
    int i = blockIdx.x * blockDim.x + threadIdx.x;
    if (i < L) mb[i] = mask[i] ? 0.f : -2.0e9f;
}

// ---------------- embedding ----------------
__global__ __launch_bounds__(256) void embed_kernel(const int* __restrict__ ids,
                                                    const int* __restrict__ pos,
                                                    const float* __restrict__ wte,
                                                    const float* __restrict__ wpe,
                                                    float* __restrict__ h) {
    int t = blockIdx.x;
    int id = ids[t];
    int p = pos[t];
    const float* we = wte + (size_t)id * D;
    const float* wp = wpe + (size_t)p * D;
    float* hr = h + (size_t)t * D;
#pragma unroll
    for (int i = 0; i < 3; ++i) {
        int d = threadIdx.x + i * 256;
        hr[d] = we[d] + wp[d];
    }
}

// ---------------- layernorm (f32 in, bf16 out) ----------------
template <bool OUTBF>
__global__ __launch_bounds__(256) void ln_kernel(const float* __restrict__ in,
                                                 const float* __restrict__ w,
                                                 const float* __restrict__ b,
                                                 float* __restrict__ outF,
                                                 ushort* __restrict__ outB) {
    __shared__ float red[2][4];
    int row = blockIdx.x;
    const float* x = in + (size_t)row * D;
    int t = threadIdx.x;
    float v0 = x[t], v1 = x[t + 256], v2 = x[t + 512];
    float s = v0 + v1 + v2;
    float ss = v0 * v0 + v1 * v1 + v2 * v2;
#pragma unroll
    for (int o = 32; o; o >>= 1) {
        s += __shfl_xor(s, o);
        ss += __shfl_xor(ss, o);
    }
    int wave = t >> 6;
    if ((t & 63) == 0) { red[0][wave] = s; red[1][wave] = ss; }
    __syncthreads();
    s = red[0][0] + red[0][1] + red[0][2] + red[0][3];
    ss = red[1][0] + red[1][1] + red[1][2] + red[1][3];
    float mean = s * (1.f / D);
    float var = ss * (1.f / D) - mean * mean;
    float rstd = rsqrtf(var + 1e-5f);
#pragma unroll
    for (int i = 0; i < 3; ++i) {
        int d = t + i * 256;
        float vv = (i == 0) ? v0 : (i == 1) ? v1 : v2;
        float y = (vv - mean) * rstd * w[d] + b[d];
        if (OUTBF) outB[(size_t)row * D + d] = f2bf(y);
        else       outF[(size_t)row * D + d] = y;
    }
}

// ---- fused split-K reduce + bias + residual(h) + LayerNorm -> bf16 (or f32) ----
template <int S, bool OUTBF>
__global__ __launch_bounds__(256) void redln_kernel(const float* __restrict__ part,
                                                    const float* __restrict__ bias,
                                                    float* __restrict__ h,
                                                    const float* __restrict__ lnw,
                                                    const float* __restrict__ lnb,
                                                    ushort* __restrict__ outB,
                                                    float* __restrict__ outF) {
    __shared__ float red[2][4];
    int row = blockIdx.x;
    int t = threadIdx.x;
    float v[3];
    float s = 0.f, ss = 0.f;
#pragma unroll
    for (int i = 0; i < 3; ++i) {
        int d = t + i * 256;
        float x = h[(size_t)row * D + d] + bias[d];
#pragma unroll
        for (int sp = 0; sp < S; ++sp)
            x += part[((size_t)sp * L + row) * D + d];
        v[i] = x;
        h[(size_t)row * D + d] = x;
        s += x;
        ss += x * x;
    }
#pragma unroll
    for (int o = 32; o; o >>= 1) {
        s += __shfl_xor(s, o);
        ss += __shfl_xor(ss, o);
    }
    int wave = t >> 6;
    if ((t & 63) == 0) { red[0][wave] = s; red[1][wave] = ss; }
    __syncthreads();
    s = red[0][0] + red[0][1] + red[0][2] + red[0][3];
    ss = red[1][0] + red[1][1] + red[1][2] + red[1][3];
    float mean = s * (1.f / D);
    float var = ss * (1.f / D) - mean * mean;
    float rstd = rsqrtf(var + 1e-5f);
#pragma unroll
    for (int i = 0; i < 3; ++i) {
        int d = t + i * 256;
        float y = (v[i] - mean) * rstd * lnw[d] + lnb[d];
        if (OUTBF) outB[(size_t)row * D + d] = f2bf(y);
        else       outF[(size_t)row * D + d] = y;
    }
}

// ---------------- transpose-cast f32 [K][N] -> bf16 [N][K], z = layer ----------------
__global__ __launch_bounds__(256) void tcast_f32(const float* __restrict__ in,
                                                 ushort* __restrict__ out,
                                                 int K, int N,
                                                 size_t inStride, size_t outStride) {
    in += blockIdx.z * inStride;
    out += blockIdx.z * outStride;
    __shared__ float tile[64][65];
    int k0 = blockIdx.y * 64, n0 = blockIdx.x * 64;
    int t = threadIdx.x;
    int cl = t & 63, rg = t >> 6;
#pragma unroll
    for (int i = 0; i < 16; ++i) {
        int r = rg + 4 * i;
        tile[r][cl] = in[(size_t)(k0 + r) * N + n0 + cl];
    }
    __syncthreads();
#pragma unroll
    for (int i = 0; i < 16; ++i) {
        int r = rg + 4 * i;
        out[(size_t)(n0 + r) * K + k0 + cl] = f2bf(tile[cl][r]);
    }
}

// ---------------- bf16 MFMA GEMM, 128x128 tile, BK=64, dbuf LDS, 1 barrier/step ----
// LDS row = 128 B (all 64 k-elems), k-permuted 16B chunks + (row&7)<<4 XOR so a
// fragment = one clean ds_read_b128.
// VSPLIT: for the QKV GEMM, cols >= 2*D (V projection) are written transposed.
// SPLITK>1: blockIdx.z splits K; f32 partials to pout.
template <int ACT, bool OUTBF, int SPLITK, bool VSPLIT>
__global__ __launch_bounds__(256) void gemm_bf16(const ushort* __restrict__ A,
                                                 const ushort* __restrict__ Bt,
                                                 const float* __restrict__ bias,
                                                 const float* __restrict__ resid,
                                                 float* __restrict__ outF,
                                                 ushort* __restrict__ outB,
                                                 float* __restrict__ pout,
                                                 ushort* __restrict__ vTout,
                                                 int M, int N, int K) {
    __shared__ __align__(16) char lds[65536];   // 2 buf x (A 16K + B 16K)
    const int tid = threadIdx.x;
    const int lane = tid & 63, w = tid >> 6;
    const int wr = w >> 1, wc = w & 1;
    const int bm = blockIdx.y * 128, bn = blockIdx.x * 128;
    const int l15 = lane & 15, l4 = lane >> 4;
    const int kLen = K / SPLITK;
    const int kStart = (SPLITK > 1) ? blockIdx.z * kLen : 0;

    // staging geometry: 256 threads over 128 rows, thread = (row, 64B-half)
    const int srow = tid >> 1, hf = tid & 1;
    const int swz = (srow & 7) << 4;
    const int rb = srow * 128;
    int offlo[4], offhi[4];
#pragma unroll
    for (int cc = 0; cc < 4; ++cc) {
        int blo = (cc & 1) * 32 + ((cc >> 1) & 1) * 8 + hf * 64;
        offlo[cc] = rb + ((blo & 0x70) ^ swz) + (blo & 15);
        int bhi = blo + 16;
        offhi[cc] = rb + ((bhi & 0x70) ^ swz) + (bhi & 15);
    }
    const int fxor = (l15 & 7) << 4;

    f32x4 acc[4][4];
#pragma unroll
    for (int m = 0; m < 4; ++m)
#pragma unroll
        for (int n = 0; n < 4; ++n)
            acc[m][n] = (f32x4){0.f, 0.f, 0.f, 0.f};

    const ushort* Ag = A + (size_t)(bm + srow) * K + kStart + hf * 32;
    const ushort* Bg = Bt + (size_t)(bn + srow) * K + kStart + hf * 32;

    uint4 ax[4], bx[4];
#pragma unroll
    for (int cc = 0; cc < 4; ++cc) {
        ax[cc] = *(const uint4*)(Ag + cc * 8);
        bx[cc] = *(const uint4*)(Bg + cc * 8);
    }

    for (int k0 = 0; k0 < kLen; k0 += 64) {
        char* Ab = lds + ((k0 >> 6) & 1) * 32768;
        char* Bb = Ab + 16384;
        {
            uint2 t0, t1;
#pragma unroll
            for (int cc = 0; cc < 4; ++cc) {
                t0.x = ax[cc].x; t0.y = ax[cc].y; t1.x = ax[cc].z; t1.y = ax[cc].w;
                *(uint2*)(Ab + offlo[cc]) = t0;
                *(uint2*)(Ab + offhi[cc]) = t1;
                t0.x = bx[cc].x; t0.y = bx[cc].y; t1.x = bx[cc].z; t1.y = bx[cc].w;
                *(uint2*)(Bb + offlo[cc]) = t0;
                *(uint2*)(Bb + offhi[cc]) = t1;
            }
        }
        __syncthreads();
        if (k0 + 64 < kLen) {
#pragma unroll
            for (int cc = 0; cc < 4; ++cc) {
                ax[cc] = *(const uint4*)(Ag + k0 + 64 + cc * 8);
                bx[cc] = *(const uint4*)(Bg + k0 + 64 + cc * 8);
            }
        }
        bf16x8 af[4][2], bfv[4][2];
#pragma unroll
        for (int m = 0; m < 4; ++m)
#pragma unroll
            for (int ks = 0; ks < 2; ++ks)
                af[m][ks] = *(const bf16x8*)(Ab + (wr * 64 + m * 16 + l15) * 128 +
                                             ((ks * 64 + l4 * 16) ^ fxor));
#pragma unroll
        for (int n = 0; n < 4; ++n)
#pragma unroll
            for (int ks = 0; ks < 2; ++ks)
                bfv[n][ks] = *(const bf16x8*)(Bb + (wc * 64 + n * 16 + l15) * 128 +
                                              ((ks * 64 + l4 * 16) ^ fxor));
#pragma unroll
        for (int m = 0; m < 4; ++m)
#pragma unroll
            for (int n = 0; n < 4; ++n) {
                acc[m][n] = __builtin_amdgcn_mfma_f32_16x16x32_bf16(
                    af[m][0], bfv[n][0], acc[m][n], 0, 0, 0);
                acc[m][n] = __builtin_amdgcn_mfma_f32_16x16x32_bf16(
                    af[m][1], bfv[n][1], acc[m][n], 0, 0, 0);
            }
        // no trailing barrier: next iter writes the OTHER buffer; its barrier
        // (collective) orders this buffer's reads vs its next overwrite.
    }

    if (SPLITK > 1) {
        const size_t sb = (size_t)blockIdx.z * M;
#pragma unroll
        for (int m = 0; m < 4; ++m)
#pragma unroll
            for (int n = 0; n < 4; ++n) {
                int col = bn + wc * 64 + n * 16 + l15;
#pragma unroll
                for (int r = 0; r < 4; ++r) {
                    int row = bm + wr * 64 + m * 16 + l4 * 4 + r;
                    pout[(sb + row) * N + col] = acc[m][n][r];
                }
            }
    } else {
#pragma unroll
        for (int m = 0; m < 4; ++m)
#pragma unroll
            for (int n = 0; n < 4; ++n) {
                int col = bn + wc * 64 + n * 16 + l15;
                int row0 = bm + wr * 64 + m * 16 + l4 * 4;
                if (VSPLIT && col >= 2 * D) {
                    union { ushort4 s; uint32_t d[2]; } pk;
                    pk.d[0] = cvt_pk_bf16(acc[m][n][0], acc[m][n][1]);
                    pk.d[1] = cvt_pk_bf16(acc[m][n][2], acc[m][n][3]);
                    *(ushort4*)(vTout + (size_t)(col - 2 * D) * L + row0) = pk.s;
                } else {
#pragma unroll
                    for (int r = 0; r < 4; ++r) {
                        int row = row0 + r;
                        float v = acc[m][n][r];
                        if (bias) v += bias[col];
                        if (ACT == 1) v = gelu_tanh(v);
                        if (resid) v += resid[(size_t)row * N + col];
                        if (OUTBF) outB[(size_t)row * N + col] = f2bf(v);
                        else       outF[(size_t)row * N + col] = v;
                    }
                }
            }
    }
}

// ------- MFMA flash attention, QBLK=64, KV-split over blockIdx.z, partials out ----
// Softmax in log2 domain; s_setprio(1) around MFMA clusters (T5, m191).
template <int NS>
__global__ __launch_bounds__(256) void attn_kernel(const ushort* __restrict__ qkv,
                                                   const ushort* __restrict__ vT,
                                                   const float* __restrict__ maskb,
                                                   float* __restrict__ po,
                                                   float* __restrict__ pm,
                                                   float* __restrict__ pl) {
    __shared__ __align__(16) char Kl[2][8192];
    __shared__ __align__(16) char Vl[2][8192];
    __shared__ float Ml[2][64];
    const int hh = blockIdx.y;
    const int sp = blockIdx.z;
    const int q0 = ((int)gridDim.x - 1 - (int)blockIdx.x) * 64;  // long blocks first
    const int tid = threadIdx.x;
    const int lane = tid & 63, w = tid >> 6;
    const int l15 = lane & 15, l4 = lane >> 4;
    const int qg = q0 + w * 16 + l15;
    const int qmin = q0 + w * 16;   // wave-uniform

    const int nt = q0 / 64 + 1;
    const int chunk = (nt + NS - 1) / NS;
    const int it0 = sp * chunk;
    int it1 = it0 + chunk;
    if (it1 > nt) it1 = nt;

    f32x4 o[4];
#pragma unroll
    for (int i = 0; i < 4; ++i) o[i] = (f32x4){0.f, 0.f, 0.f, 0.f};
    float mrun = -1e30f, lrun = 0.f;

    if (it0 < it1) {
        bf16x8 qf[2];
#pragma unroll
        for (int ks = 0; ks < 2; ++ks)
            qf[ks] = ldfrag(qkv + (size_t)qg * QKVN + hh * 64 + ks * 32 + l4 * 4);

        const int srow = tid >> 2, c = tid & 3;
        const int blo = (c & 1) * 32 + (c >> 1) * 8;
        const int swz = (srow & 7) << 4;
        const int rb = srow * 128;
        const int lo4 = blo & 15;
        const int s0 = rb + (((blo)      & 0x70) ^ swz) + lo4;
        const int s1 = rb + (((blo + 16) & 0x70) ^ swz) + lo4;
        const int s2 = rb + (((blo + 64) & 0x70) ^ swz) + lo4;
        const int s3 = rb + (((blo + 80) & 0x70) ^ swz) + lo4;
        const int fxor = (l15 & 7) << 4;

        const ushort* Ksrc = qkv + (size_t)srow * QKVN + D + hh * 64 + c * 8;
        const ushort* Vsrc = vT + (size_t)(hh * 64 + srow) * L + c * 8;

        uint4 ka, kb, va, vb;
        float mv = 0.f;
        {
            const size_t koff = (size_t)(it0 * 64) * QKVN;
            ka = *(const uint4*)(Ksrc + koff);
            kb = *(const uint4*)(Ksrc + koff + 32);
            va = *(const uint4*)(Vsrc + it0 * 64);
            vb = *(const uint4*)(Vsrc + it0 * 64 + 32);
            if (tid < 64) mv = maskb[it0 * 64 + tid];
        }

        for (int it = it0; it < it1; ++it) {
            const int kv0 = it * 64;
            const int b = it & 1;
            {
                char* Kb = Kl[b];
                char* Vb = Vl[b];
                uint2 t0, t1;
                t0.x = ka.x; t0.y = ka.y; t1.x = ka.z; t1.y = ka.w;
                *(uint2*)(Kb + s0) = t0;
                *(uint2*)(Kb + s1) = t1;
                t0.x = kb.x; t0.y = kb.y; t1.x = kb.z; t1.y = kb.w;
                *(uint2*)(Kb + s2) = t0;
                *(uint2*)(Kb + s3) = t1;
                t0.x = va.x; t0.y = va.y; t1.x = va.z; t1.y = va.w;
                *(uint2*)(Vb + s0) = t0;
                *(uint2*)(Vb + s1) = t1;
                t0.x = vb.x; t0.y = vb.y; t1.x = vb.z; t1.y = vb.w;
                *(uint2*)(Vb + s2) = t0;
                *(uint2*)(Vb + s3) = t1;
                if (tid < 64) Ml[b][tid] = mv;
            }
            __syncthreads();
            if (it + 1 < it1) {
                const size_t koff = (size_t)(kv0 + 64) * QKVN;
                ka = *(const uint4*)(Ksrc + koff);
                kb = *(const uint4*)(Ksrc + koff + 32);
                va = *(const uint4*)(Vsrc + kv0 + 64);
                vb = *(const uint4*)(Vsrc + kv0 + 96);
                if (tid < 64) mv = maskb[kv0 + 64 + tid];
            }

            const char* Kb = Kl[b];
            const char* Vb = Vl[b];

            f32x4 st[4];
#pragma unroll
            for (int m = 0; m < 4; ++m) st[m] = (f32x4){0.f, 0.f, 0.f, 0.f};
            __builtin_amdgcn_s_setprio(1);
#pragma unroll
            for (int m = 0; m < 4; ++m)
#pragma unroll
                for (int ks = 0; ks < 2; ++ks) {
                    bf16x8 kf = *(const bf16x8*)(Kb + (m * 16 + l15) * 128 +
                                                 ((ks * 64 + l4 * 16) ^ fxor));
                    st[m] = __builtin_amdgcn_mfma_f32_16x16x32_bf16(kf, qf[ks], st[m], 0, 0, 0);
                }
            __builtin_amdgcn_s_setprio(0);

            float p[4][4];
            float tmax = -1e30f;
            const bool full = (kv0 + 63 <= qmin);
            if (full) {
#pragma unroll
                for (int m = 0; m < 4; ++m)
#pragma unroll
                    for (int r = 0; r < 4; ++r) {
                        int kl = m * 16 + l4 * 4 + r;
                        float s = fmaf(st[m][r], LOG2E, Ml[b][kl]);
                        p[m][r] = s;
                        tmax = fmaxf(tmax, s);
                    }
            } else {
#pragma unroll
                for (int m = 0; m < 4; ++m)
#pragma unroll
                    for (int r = 0; r < 4; ++r) {
                        int kl = m * 16 + l4 * 4 + r;
                        float s = fmaf(st[m][r], LOG2E, Ml[b][kl]);
                        if (kv0 + kl > qg) s = -1e30f;
                        p[m][r] = s;
                        tmax = fmaxf(tmax, s);
                    }
            }
            tmax = fmaxf(tmax, __shfl_xor(tmax, 16));
            tmax = fmaxf(tmax, __shfl_xor(tmax, 32));
            const bool noresc = __all(tmax <= mrun);
            float mnew = noresc ? mrun : fmaxf(mrun, tmax);
            float scale = noresc ? 1.f : ex2(mrun - mnew);
            float ts = 0.f;
#pragma unroll
            for (int m = 0; m < 4; ++m)
#pragma unroll
                for (int r = 0; r < 4; ++r) {
                    float e = ex2(p[m][r] - mnew);
                    p[m][r] = e;
                    ts += e;
                }
            ts += __shfl_xor(ts, 16);
            ts += __shfl_xor(ts, 32);
            lrun = lrun * scale + ts;
            mrun = mnew;

            bf16x8 pf[2];
#pragma unroll
            for (int g = 0; g < 2; ++g) {
                union { bf16x8 v; uint32_t d[4]; } pu;
                pu.d[0] = cvt_pk_bf16(p[2 * g][0], p[2 * g][1]);
                pu.d[1] = cvt_pk_bf16(p[2 * g][2], p[2 * g][3]);
                pu.d[2] = cvt_pk_bf16(p[2 * g + 1][0], p[2 * g + 1][1]);
                pu.d[3] = cvt_pk_bf16(p[2 * g + 1][2], p[2 * g + 1][3]);
                pf[g] = pu.v;
            }
            if (!noresc) {
#pragma unroll
                for (int i = 0; i < 4; ++i) {
                    o[i][0] *= scale; o[i][1] *= scale; o[i][2] *= scale; o[i][3] *= scale;
                }
            }
            __builtin_amdgcn_s_setprio(1);
#pragma unroll
            for (int dhb = 0; dhb < 4; ++dhb)
#pragma unroll
                for (int g = 0; g < 2; ++g) {
                    bf16x8 vf = *(const bf16x8*)(Vb + (dhb * 16 + l15) * 128 +
                                                 ((g * 64 + l4 * 16) ^ fxor));
                    o[dhb] = __builtin_amdgcn_mfma_f32_16x16x32_bf16(vf, pf[g], o[dhb], 0, 0, 0);
                }
            __builtin_amdgcn_s_setprio(0);
        }
    }

    // write partials (o f32, m in log2 units, l)
    const size_t pb = (size_t)(sp * H + hh) * L + qg;
    if (l4 == 0) { pm[pb] = mrun; pl[pb] = lrun; }
    float* op = po + pb * 64;
#pragma unroll
    for (int dhb = 0; dhb < 4; ++dhb)
        *(f32x4*)(op + dhb * 16 + l4 * 4) = o[dhb];
}

// ---------------- flash combine (log2 domain): merge NS partials -> bf16 ctx ----
template <int NS>
__global__ __launch_bounds__(256) void attn_combine(const float* __restrict__ po,
                                                    const float* __restrict__ pm,
                                                    const float* __restrict__ pl,
                                                    ushort* __restrict__ ctx) {
    const int hh = blockIdx.y;
    const int q = blockIdx.x * 64 + (threadIdx.x >> 2);
    const int d0 = (threadIdx.x & 3) * 16;
    size_t idx[NS];
    float mm = -1e30f;
#pragma unroll
    for (int s = 0; s < NS; ++s) {
        idx[s] = (size_t)(s * H + hh) * L + q;
        mm = fmaxf(mm, pm[idx[s]]);
    }
    float e[NS];
    float l = 0.f;
#pragma unroll
    for (int s = 0; s < NS; ++s) {
        e[s] = ex2(pm[idx[s]] - mm);
        l += pl[idx[s]] * e[s];
    }
    float rinv = 1.0f / l;
    ushort* cp = ctx + (size_t)q * D + hh * 64 + d0;
#pragma unroll
    for (int j = 0; j < 16; j += 4) {
        float acc[4] = {0.f, 0.f, 0.f, 0.f};
#pragma unroll
        for (int s = 0; s < NS; ++s) {
            const float* op = po + idx[s] * 64 + d0 + j;
            float4 v = *(const float4*)op;
            acc[0] += v.x * e[s];
            acc[1] += v.y * e[s];
            acc[2] += v.z * e[s];
            acc[3] += v.w * e[s];
        }
        ushort4 pk;
        pk.x = f2bf(acc[0] * rinv);
        pk.y = f2bf(acc[1] * rinv);
        pk.z = f2bf(acc[2] * rinv);
        pk.w = f2bf(acc[3] * rinv);
        *(ushort4*)(cp + j) = pk;
    }
}

extern "C" void kernel_launch(void* const* d_in, const int* in_sizes, int n_in,
                              void* d_out, int out_size, void* d_ws, size_t ws_size,
                              hipStream_t stream) {
    const int* ids = (const int*)d_in[0];
    const int* amask = (const int*)d_in[1];
    const float* wte = (const float*)d_in[2];
    const float* wpe = (const float*)d_in[3];
    const float* lnf_w = (const float*)d_in[4];
    const float* lnf_b = (const float*)d_in[5];
    const float* ln1_w = (const float*)d_in[6];
    const float* ln1_b = (const float*)d_in[7];
    const float* qw = (const float*)d_in[8];
    const float* kw = (const float*)d_in[9];
    const float* vw = (const float*)d_in[10];
    const float* ow = (const float*)d_in[11];
    const float* ob = (const float*)d_in[12];
    const float* ln2_w = (const float*)d_in[13];
    const float* ln2_b = (const float*)d_in[14];
    const float* fcw = (const float*)d_in[15];
    const float* fcb = (const float*)d_in[16];
    const float* pw = (const float*)d_in[17];
    const float* pb = (const float*)d_in[18];

    char* p = (char*)d_ws;
    auto take = [&](size_t bytes) -> char* {
        char* r = p;
        p += (bytes + 4095) & ~(size_t)4095;
        return r;
    };
    ushort* wqkvT = (ushort*)take((size_t)NL * QKVN * D * 2);
    ushort* woT   = (ushort*)take((size_t)NL * D * D * 2);
    ushort* fcwT  = (ushort*)take((size_t)NL * F * D * 2);
    ushort* pwT   = (ushort*)take((size_t)NL * D * F * 2);
    float*  h     = (float*)take((size_t)L * D * 4);
    ushort* xb    = (ushort*)take((size_t)L * D * 2);
    ushort* qkvb  = (ushort*)take((size_t)L * QKVN * 2);
    ushort* vTb   = (ushort*)take((size_t)D * L * 2);
    ushort* ctxb  = (ushort*)take((size_t)L * D * 2);
    ushort* f1b   = (ushort*)take((size_t)L * F * 2);
    float*  pk    = (float*)take((size_t)4 * L * D * 4);      // split-K partials
    float*  po    = (float*)take((size_t)4 * H * L * 64 * 4); // attn o partials (NS=4)
    float*  pm    = (float*)take((size_t)4 * H * L * 4);
    float*  pl    = (float*)take((size_t)4 * H * L * 4);
    float*  mb    = (float*)take(L * 4);
    int*    pos   = (int*)take(L * 4);

    pos_kernel<<<8, 256, 0, stream>>>(amask, pos);
    maskb_kernel<<<8, 256, 0, stream>>>(amask, mb);
    embed_kernel<<<L, 256, 0, stream>>>(ids, pos, wte, wpe, h);

    tcast_f32<<<dim3(12, 12, NL), 256, 0, stream>>>(qw, wqkvT, D, D,
                                                    (size_t)D * D, (size_t)QKVN * D);
    tcast_f32<<<dim3(12, 12, NL), 256, 0, stream>>>(kw, wqkvT + (size_t)D * D, D, D,
                                                    (size_t)D * D, (size_t)QKVN * D);
    tcast_f32<<<dim3(12, 12, NL), 256, 0, stream>>>(vw, wqkvT + (size_t)2 * D * D, D, D,
                                                    (size_t)D * D, (size_t)QKVN * D);
    tcast_f32<<<dim3(12, 12, NL), 256, 0, stream>>>(ow, woT, D, D,
                                                    (size_t)D * D, (size_t)D * D);
    tcast_f32<<<dim3(48, 12, NL), 256, 0, stream>>>(fcw, fcwT, D, F,
                                                    (size_t)D * F, (size_t)F * D);
    tcast_f32<<<dim3(12, 48, NL), 256, 0, stream>>>(pw, pwT, F, D,
                                                    (size_t)F * D, (size_t)D * F);

    ln_kernel<true><<<L, 256, 0, stream>>>(h, ln1_w, ln1_b, nullptr, xb);

    for (int l = 0; l < NL; ++l) {
        gemm_bf16<0, true, 1, true><<<dim3(QKVN / 128, L / 128), 256, 0, stream>>>(
            xb, wqkvT + (size_t)l * QKVN * D, nullptr, nullptr, nullptr, qkvb, nullptr,
            vTb, L, QKVN, D);
        attn_kernel<4><<<dim3(L / 64, H, 4), 256, 0, stream>>>(qkvb, vTb, mb,
                                                               po, pm, pl);
        attn_combine<4><<<dim3(L / 64, H), 256, 0, stream>>>(po, pm, pl, ctxb);
        gemm_bf16<0, true, 3, false><<<dim3(D / 128, L / 128, 3), 256, 0, stream>>>(
            ctxb, woT + (size_t)l * D * D, nullptr, nullptr, nullptr, nullptr, pk,
            nullptr, L, D, D);
        redln_kernel<3, true><<<L, 256, 0, stream>>>(
            pk, ob + l * D, h, ln2_w + l * D, ln2_b + l * D, xb, nullptr);
        gemm_bf16<1, true, 1, false><<<dim3(F / 128, L / 128), 256, 0, stream>>>(
            xb, fcwT + (size_t)l * F * D, fcb + l * F, nullptr, nullptr, f1b, nullptr,
            nullptr, L, F, D);
        gemm_bf16<0, true, 4, false><<<dim3(D / 128, L / 128, 4), 256, 0, stream>>>(
            f1b, pwT + (size_t)l * D * F, nullptr, nullptr, nullptr, nullptr, pk,
            nullptr, L, D, F);
        if (l < NL - 1) {
            redln_kernel<4, true><<<L, 256, 0, stream>>>(
                pk, pb + l * D, h, ln1_w + (l + 1) * D, ln1_b + (l + 1) * D, xb, nullptr);
        } else {
            redln_kernel<4, false><<<L, 256, 0, stream>>>(
                pk, pb + l * D, h, lnf_w, lnf_b, nullptr, (float*)d_out);
        }
    }
}